// Round 1
// baseline (3470.501 us; speedup 1.0000x reference)
//
#include <hip/hip_runtime.h>

#define F 128
#define MGCS 60
#define NWIN 800
#define RFS 512
#define NBLK 4
#define NLAY 9
#define SQF 0.70710678118f

// ---------------- precompute kernels ----------------

// cond[n][m] = tanh(mgc[n/200] . cond_w[(n%200)*60+m] + cond_b[...])
__global__ void k_cond(const float* __restrict__ mgc, const float* __restrict__ cond_w,
                       const float* __restrict__ cond_b, float* __restrict__ cond) {
  int i = blockIdx.x * blockDim.x + threadIdx.x;
  if (i >= NWIN * MGCS) return;
  int n = i / MGCS, m = i % MGCS;
  int t = n / 200, u = n % 200;
  const float* wrow = cond_w + (size_t)(u * MGCS + m) * MGCS;
  const float* mr = mgc + t * MGCS;
  float s = cond_b[u * MGCS + m];
#pragma unroll
  for (int k = 0; k < MGCS; ++k) s += mr[k] * wrow[k];
  cond[i] = tanhf(s);
}

// CI[w][n][f] = cond[n] . condlin_w[w][f] + condlin_b[w][f],  w = (blk*9+l)*2+t
__global__ void k_ci(const float* __restrict__ cond, const float* __restrict__ clw,
                     const float* __restrict__ clb, float* __restrict__ CI) {
  int b = blockIdx.x;                  // w*800 + n
  int n = b % NWIN, w = b / NWIN;
  __shared__ float cs[MGCS];
  int tid = threadIdx.x;               // 128 threads = f
  if (tid < MGCS) cs[tid] = cond[n * MGCS + tid];
  __syncthreads();
  const float* wr = clw + (size_t)(w * F + tid) * MGCS;
  float s = clb[w * F + tid];
#pragma unroll
  for (int k = 0; k < MGCS; ++k) s += cs[k] * wr[k];
  CI[((size_t)w * NWIN + n) * F + tid] = s;
}

// Wt[blk][lm][ck][tf] = convL_w[blk][lm][t][f][c][k],  ck = k*128+c, tf = t*128+f
__global__ void k_wt(const float* __restrict__ convL_w, float* __restrict__ Wt) {
  int i = blockIdx.x * blockDim.x + threadIdx.x;
  const int total = NBLK * 8 * 256 * 384;
  if (i >= total) return;
  int tf = i % 384; int rest = i / 384;
  int ck = rest % 256; rest /= 256;
  int lm = rest % 8; int blk = rest / 8;
  int t = tf / F, f = tf % F;
  int k = ck >> 7, c = ck & (F - 1);
  Wt[i] = convL_w[((((size_t)((blk * 8 + lm) * 3 + t) * F + f) * F + c) * 2) + k];
}

__global__ void k_outsig(const float* __restrict__ signal, float* __restrict__ out) {
  int i = blockIdx.x * blockDim.x + threadIdx.x;
  if (i < NWIN) out[i] = signal[RFS + i];
}

// ---------------- per-block kernels ----------------

// layer 0 (Cin=1) fused with window gather. out[n][j][f], j<256.
__global__ void k_layer0(const float* __restrict__ prev, const float* __restrict__ w0,
                         const float* __restrict__ b0, const float* __restrict__ CIb,
                         float* __restrict__ out) {
  int i = blockIdx.x * blockDim.x + threadIdx.x;
  if (i >= NWIN * 256 * F) return;
  int f = i & (F - 1);
  int rest = i >> 7;
  int j = rest & 255;
  int n = rest >> 8;
  float x0 = prev[n + 2 * j], x1 = prev[n + 2 * j + 1];
  float o0 = b0[f]         + x0 * w0[(0 * F + f) * 2] + x1 * w0[(0 * F + f) * 2 + 1]
           + CIb[(size_t)n * F + f];
  float o1 = b0[F + f]     + x0 * w0[(1 * F + f) * 2] + x1 * w0[(1 * F + f) * 2 + 1]
           + CIb[(size_t)NWIN * F + (size_t)n * F + f];
  float o2 = b0[2 * F + f] + x0 * w0[(2 * F + f) * 2] + x1 * w0[(2 * F + f) * 2 + 1];
  float it = tanhf(o0);
  float gt = 1.f / (1.f + expf(-o1));
  out[i] = (it * gt + o2) * SQF;
}

// GEMM: C[M][384] = A[M][256] * Wt[256][384], + bias/CI + gated activation -> out[M][128]
#define BM 64
#define BK 64
#define BNF 64
__global__ __launch_bounds__(256) void k_gemm(
    const float* __restrict__ A, const float* __restrict__ Wt,
    const float* __restrict__ bias, const float* __restrict__ CI0,
    const float* __restrict__ CI1, float* __restrict__ out, int M, int Lout) {
  __shared__ __align__(16) float As[BK][BM + 4];      // k-major
  __shared__ __align__(16) float Bs[3][BK][BNF + 4];
  int m0 = blockIdx.x * BM;
  int f0 = blockIdx.y * BNF;
  int tid = threadIdx.x;
  int tm = tid & 15, tf = tid >> 4;    // 16 x 16 threads, 4x4 micro-tile per gate
  float acc[3][4][4] = {};
  for (int k0 = 0; k0 < 256; k0 += BK) {
#pragma unroll
    for (int it = 0; it < 4; ++it) {   // stage A: 1024 float4
      int idx = tid + it * 256;
      int r = idx >> 4;
      int kq = idx & 15;
      float4 v = make_float4(0.f, 0.f, 0.f, 0.f);
      if (m0 + r < M)
        v = *reinterpret_cast<const float4*>(A + (size_t)(m0 + r) * 256 + k0 + kq * 4);
      As[kq * 4 + 0][r] = v.x; As[kq * 4 + 1][r] = v.y;
      As[kq * 4 + 2][r] = v.z; As[kq * 4 + 3][r] = v.w;
    }
#pragma unroll
    for (int it = 0; it < 12; ++it) {  // stage B: 3072 float4
      int idx = tid + it * 256;
      int t = idx >> 10;
      int rr = (idx >> 4) & 63;
      int fq = idx & 15;
      float4 v = *reinterpret_cast<const float4*>(
          Wt + (size_t)(0 + (k0 + rr)) * 384 + t * F + f0 + fq * 4);
      *reinterpret_cast<float4*>(&Bs[t][rr][fq * 4]) = v;
    }
    __syncthreads();
#pragma unroll
    for (int kk = 0; kk < BK; ++kk) {
      float a[4];
      *reinterpret_cast<float4*>(a) = *reinterpret_cast<const float4*>(&As[kk][tm * 4]);
      float b[3][4];
#pragma unroll
      for (int t = 0; t < 3; ++t)
        *reinterpret_cast<float4*>(b[t]) = *reinterpret_cast<const float4*>(&Bs[t][kk][tf * 4]);
#pragma unroll
      for (int t = 0; t < 3; ++t)
#pragma unroll
        for (int i2 = 0; i2 < 4; ++i2)
#pragma unroll
          for (int j2 = 0; j2 < 4; ++j2)
            acc[t][i2][j2] += a[i2] * b[t][j2];
    }
    __syncthreads();
  }
#pragma unroll
  for (int i2 = 0; i2 < 4; ++i2) {
    int m = m0 + tm * 4 + i2;
    if (m >= M) continue;
    int n = m / Lout;
    float4 res;
    float* rp = &res.x;
#pragma unroll
    for (int j2 = 0; j2 < 4; ++j2) {
      int f = f0 + tf * 4 + j2;
      float o0 = acc[0][i2][j2] + bias[f]         + CI0[(size_t)n * F + f];
      float o1 = acc[1][i2][j2] + bias[F + f]     + CI1[(size_t)n * F + f];
      float o2 = acc[2][i2][j2] + bias[2 * F + f];
      float itv = tanhf(o0);
      float gtv = 1.f / (1.f + expf(-o1));
      rp[j2] = (itv * gtv + o2) * SQF;
    }
    *reinterpret_cast<float4*>(out + (size_t)m * F + f0 + tf * 4) = res;
  }
}

// head: pre = relu(H @ pre_w^T + pre_b); mean/logvar; reparam; feedback + outputs
__global__ __launch_bounds__(256) void k_head(
    const float* __restrict__ H, const float* __restrict__ pre_w,
    const float* __restrict__ pre_b, const float* __restrict__ mean_w,
    const float* __restrict__ mean_b, const float* __restrict__ std_w,
    const float* __restrict__ std_b, const float* __restrict__ eps,
    const float* __restrict__ signal, float* __restrict__ prev_next,
    float* __restrict__ out_mean, float* __restrict__ out_logvar,
    float* __restrict__ out_tails) {
  int n = blockIdx.x;
  int tid = threadIdx.x;
  __shared__ float hv[F];
  __shared__ float red[8];
  if (tid < F) hv[tid] = H[(size_t)n * F + tid];
  __syncthreads();
  const float* wr = pre_w + (size_t)tid * F;
  float s = pre_b[tid];
#pragma unroll
  for (int c = 0; c < F; ++c) s += hv[c] * wr[c];
  float p = fmaxf(s, 0.f);
  float m_c = p * mean_w[tid];
  float v_c = p * std_w[tid];
#pragma unroll
  for (int off = 32; off > 0; off >>= 1) {
    m_c += __shfl_down(m_c, off);
    v_c += __shfl_down(v_c, off);
  }
  int wid = tid >> 6;
  if ((tid & 63) == 0) { red[wid] = m_c; red[4 + wid] = v_c; }
  __syncthreads();
  if (tid == 0) {
    float mean = red[0] + red[1] + red[2] + red[3] + mean_b[0];
    float logv = red[4] + red[5] + red[6] + red[7] + std_b[0];
    float nx = eps[n] * expf(0.5f * logv) + mean;
    if (prev_next) prev_next[RFS + n] = nx;
    if (out_mean) { out_mean[n] = mean; out_logvar[n] = logv; }
    if (n >= NWIN - RFS) out_tails[n - (NWIN - RFS)] = nx;
  }
  if (tid == 1 && prev_next && n < RFS) prev_next[n] = signal[n];
}

// ---------------- host ----------------

extern "C" void kernel_launch(void* const* d_in, const int* in_sizes, int n_in,
                              void* d_out, int out_size, void* d_ws, size_t ws_size,
                              hipStream_t stream) {
  const float* mgc      = (const float*)d_in[0];
  const float* signal   = (const float*)d_in[1];
  const float* cond_w   = (const float*)d_in[2];
  const float* cond_b   = (const float*)d_in[3];
  const float* conv0_w  = (const float*)d_in[4];
  const float* conv0_b  = (const float*)d_in[5];
  const float* convL_w  = (const float*)d_in[6];
  const float* convL_b  = (const float*)d_in[7];
  const float* condlin_w= (const float*)d_in[8];
  const float* condlin_b= (const float*)d_in[9];
  const float* pre_w    = (const float*)d_in[10];
  const float* pre_b    = (const float*)d_in[11];
  const float* mean_w   = (const float*)d_in[12];
  const float* mean_b   = (const float*)d_in[13];
  const float* std_w    = (const float*)d_in[14];
  const float* std_b    = (const float*)d_in[15];
  const float* eps      = (const float*)d_in[16];
  float* out = (float*)d_out;

  float* ws    = (float*)d_ws;
  float* cond  = ws;                       // 48,000
  float* CI    = cond + 48000;             // 72*800*128 = 7,372,800
  float* Wt    = CI + 7372800;             // 4*8*256*384 = 3,145,728
  float* prevb = Wt + 3145728;             // 4*1312
  float* bufA  = prevb + 4 * 1312;         // 800*256*128 = 26,214,400
  float* bufB  = bufA + 26214400;          // 800*128*128 = 13,107,200

  k_cond<<<(NWIN * MGCS + 255) / 256, 256, 0, stream>>>(mgc, cond_w, cond_b, cond);
  k_ci<<<72 * NWIN, 128, 0, stream>>>(cond, condlin_w, condlin_b, CI);
  k_wt<<<(NBLK * 8 * 256 * 384 + 255) / 256, 256, 0, stream>>>(convL_w, Wt);
  k_outsig<<<(NWIN + 255) / 256, 256, 0, stream>>>(signal, out);

  for (int blk = 0; blk < NBLK; ++blk) {
    const float* prev = (blk == 0) ? signal : (prevb + (size_t)(blk - 1) * 1312);
    const float* CIb = CI + (size_t)(blk * NLAY) * 2 * NWIN * F;
    k_layer0<<<(NWIN * 256 * F + 255) / 256, 256, 0, stream>>>(
        prev, conv0_w + (size_t)blk * 3 * F * 2, conv0_b + (size_t)blk * 3 * F, CIb, bufA);

    float* cur = bufA;
    float* nxt = bufB;
    for (int l = 1; l < NLAY; ++l) {
      int Lout = 256 >> l;
      int M = NWIN * Lout;
      const float* ci0 = CI + ((size_t)((blk * NLAY + l) * 2 + 0)) * NWIN * F;
      const float* ci1 = CI + ((size_t)((blk * NLAY + l) * 2 + 1)) * NWIN * F;
      const float* wt  = Wt + (size_t)(blk * 8 + (l - 1)) * 256 * 384;
      const float* bs  = convL_b + (size_t)((blk * 8 + (l - 1)) * 3) * F;
      dim3 grid((M + BM - 1) / BM, F / BNF);
      k_gemm<<<grid, 256, 0, stream>>>(cur, wt, bs, ci0, ci1, nxt, M, Lout);
      float* tmp = cur; cur = nxt; nxt = tmp;
    }
    // cur now holds [800][128] (L=1)
    k_head<<<NWIN, 256, 0, stream>>>(
        cur, pre_w + (size_t)blk * 256 * F, pre_b + (size_t)blk * 256,
        mean_w + (size_t)blk * 256, mean_b + blk,
        std_w + (size_t)blk * 256, std_b + blk,
        eps + (size_t)blk * NWIN, signal,
        (blk < 3) ? (prevb + (size_t)blk * 1312) : nullptr,
        (blk == 3) ? (out + 800) : nullptr,
        (blk == 3) ? (out + 1600) : nullptr,
        out + 2400 + (size_t)blk * 512);
  }
}

// Round 2
// 1540.014 us; speedup vs baseline: 2.2536x; 2.2536x over previous
//
#include <hip/hip_runtime.h>
#include <hip/hip_bf16.h>

#define F 128
#define MGCS 60
#define NWIN 800
#define RFS 512
#define NBLK 4
#define NLAY 9
#define SQF 0.70710678118f

typedef __attribute__((ext_vector_type(8))) short s16x8;
typedef __attribute__((ext_vector_type(4))) float f32x4;

__device__ __forceinline__ float fast_tanh(float x) {
  float e = __expf(2.f * x);
  return 1.f - 2.f / (e + 1.f);
}
__device__ __forceinline__ float fast_sig(float x) {
  return 1.f / (1.f + __expf(-x));
}

// ---------------- precompute kernels ----------------

__global__ void k_cond(const float* __restrict__ mgc, const float* __restrict__ cond_w,
                       const float* __restrict__ cond_b, float* __restrict__ cond) {
  int i = blockIdx.x * blockDim.x + threadIdx.x;
  if (i >= NWIN * MGCS) return;
  int n = i / MGCS, m = i % MGCS;
  int t = n / 200, u = n % 200;
  const float* wrow = cond_w + (size_t)(u * MGCS + m) * MGCS;
  const float* mr = mgc + t * MGCS;
  float s = cond_b[u * MGCS + m];
#pragma unroll
  for (int k = 0; k < MGCS; ++k) s += mr[k] * wrow[k];
  cond[i] = tanhf(s);
}

__global__ void k_ci(const float* __restrict__ cond, const float* __restrict__ clw,
                     const float* __restrict__ clb, float* __restrict__ CI) {
  int b = blockIdx.x;                  // w*800 + n
  int n = b % NWIN, w = b / NWIN;
  __shared__ float cs[MGCS];
  int tid = threadIdx.x;               // 128 threads = f
  if (tid < MGCS) cs[tid] = cond[n * MGCS + tid];
  __syncthreads();
  const float* wr = clw + (size_t)(w * F + tid) * MGCS;
  float s = clb[w * F + tid];
#pragma unroll
  for (int k = 0; k < MGCS; ++k) s += cs[k] * wr[k];
  CI[((size_t)w * NWIN + n) * F + tid] = s;
}

// W2[wl][tf][k] (bf16) = convL_w[blk][lm][t][f][c][k2], tf = t*128+f, k = k2*128+c
__global__ void k_wt(const float* __restrict__ convL_w, __hip_bfloat16* __restrict__ W2) {
  int i = blockIdx.x * blockDim.x + threadIdx.x;
  const int total = NBLK * 8 * 384 * 256;
  if (i >= total) return;
  int k = i & 255;
  int tf = (i >> 8) % 384;
  int wl = i / (384 * 256);
  int t = tf >> 7, f = tf & 127;
  int k2 = k >> 7, c = k & 127;
  W2[i] = __float2bfloat16(convL_w[(((size_t)(wl * 3 + t) * 128 + f) * 128 + c) * 2 + k2]);
}

__global__ void k_outsig(const float* __restrict__ signal, float* __restrict__ out) {
  int i = blockIdx.x * blockDim.x + threadIdx.x;
  if (i < NWIN) out[i] = signal[RFS + i];
}

// ---------------- per-block kernels ----------------

// layer 0 (Cin=1) fused with window gather. out[n][j][f] bf16, j<256.
__global__ void k_layer0(const float* __restrict__ prev, const float* __restrict__ w0,
                         const float* __restrict__ b0, const float* __restrict__ CIb,
                         __hip_bfloat16* __restrict__ out) {
  int i = blockIdx.x * blockDim.x + threadIdx.x;
  if (i >= NWIN * 256 * F) return;
  int f = i & (F - 1);
  int rest = i >> 7;
  int j = rest & 255;
  int n = rest >> 8;
  float x0 = prev[n + 2 * j], x1 = prev[n + 2 * j + 1];
  float o0 = b0[f]         + x0 * w0[(0 * F + f) * 2] + x1 * w0[(0 * F + f) * 2 + 1]
           + CIb[(size_t)n * F + f];
  float o1 = b0[F + f]     + x0 * w0[(1 * F + f) * 2] + x1 * w0[(1 * F + f) * 2 + 1]
           + CIb[(size_t)NWIN * F + (size_t)n * F + f];
  float o2 = b0[2 * F + f] + x0 * w0[(2 * F + f) * 2] + x1 * w0[(2 * F + f) * 2 + 1];
  out[i] = __float2bfloat16((fast_tanh(o0) * fast_sig(o1) + o2) * SQF);
}

// MFMA GEMM: out[M][128] = act(A[M][256] x W2[384][256]^T + bias + CI)
// block: 512 threads = 8 waves (2m x 4f), BM=128, full K in LDS (swizzled), B from L2.
__global__ __launch_bounds__(512, 2) void k_gemm(
    const __hip_bfloat16* __restrict__ A, const __hip_bfloat16* __restrict__ W2,
    const float* __restrict__ bias, const float* __restrict__ CI0,
    const float* __restrict__ CI1, __hip_bfloat16* __restrict__ out,
    int M, int lgL) {
  __shared__ char AsB[128 * 512];                 // 64 KB, rows swizzled by ((row&7)<<4)
  const int tid = threadIdx.x;
  const int lane = tid & 63, wid = tid >> 6;
  const int m0 = blockIdx.x * 128;
  const char* Ab = (const char*)A + (size_t)m0 * 512;
  {
    const int half = lane >> 5;
    const int lin = (lane & 31) * 16;
#pragma unroll
    for (int it = 0; it < 8; ++it) {
      int inst = wid * 8 + it;
      int row = inst * 2 + half;
      int src = row * 512 + (lin ^ ((row & 7) << 4));   // inverse-swizzled source
      __builtin_amdgcn_global_load_lds(
          (const __attribute__((address_space(1))) unsigned int*)(Ab + src),
          (__attribute__((address_space(3))) unsigned int*)(AsB + inst * 1024), 16, 0, 0);
    }
  }
  __syncthreads();

  const int wm = wid & 1, wf = wid >> 1;          // wave tile: 64m x 32f
  const int col = lane & 15, kg = lane >> 4;
  f32x4 acc[4][2][3];
#pragma unroll
  for (int mf = 0; mf < 4; ++mf)
#pragma unroll
    for (int ff = 0; ff < 2; ++ff)
#pragma unroll
      for (int g = 0; g < 3; ++g) acc[mf][ff][g] = (f32x4)(0.f);

  const char* Wb = (const char*)W2;
#pragma unroll
  for (int ks = 0; ks < 8; ++ks) {
    s16x8 afr[4];
#pragma unroll
    for (int mf = 0; mf < 4; ++mf) {
      int row = wm * 64 + mf * 16 + col;
      int off = row * 512 + ((ks * 64 + kg * 16) ^ ((row & 7) << 4));
      afr[mf] = *(const s16x8*)(AsB + off);
    }
#pragma unroll
    for (int ff = 0; ff < 2; ++ff)
#pragma unroll
      for (int g = 0; g < 3; ++g) {
        int tf = g * 128 + wf * 32 + ff * 16 + col;
        s16x8 bfr = *(const s16x8*)(Wb + (size_t)tf * 512 + ks * 64 + kg * 16);
#pragma unroll
        for (int mf = 0; mf < 4; ++mf)
          acc[mf][ff][g] =
              __builtin_amdgcn_mfma_f32_16x16x32_bf16(afr[mf], bfr, acc[mf][ff][g], 0, 0, 0);
      }
  }

#pragma unroll
  for (int mf = 0; mf < 4; ++mf) {
    int mb = m0 + wm * 64 + mf * 16 + kg * 4;
#pragma unroll
    for (int ff = 0; ff < 2; ++ff) {
      int f = wf * 32 + ff * 16 + col;
      float b0 = bias[f], b1 = bias[128 + f], b2 = bias[256 + f];
#pragma unroll
      for (int r = 0; r < 4; ++r) {
        int m = mb + r;
        if (m < M) {
          int n = m >> lgL;
          float o0 = acc[mf][ff][0][r] + b0 + CI0[n * 128 + f];
          float o1 = acc[mf][ff][1][r] + b1 + CI1[n * 128 + f];
          float o2 = acc[mf][ff][2][r] + b2;
          out[(size_t)m * 128 + f] =
              __float2bfloat16((fast_tanh(o0) * fast_sig(o1) + o2) * SQF);
        }
      }
    }
  }
}

// head: pre = relu(H @ pre_w^T + pre_b); mean/logvar; reparam; feedback + outputs
__global__ __launch_bounds__(256) void k_head(
    const __hip_bfloat16* __restrict__ H, const float* __restrict__ pre_w,
    const float* __restrict__ pre_b, const float* __restrict__ mean_w,
    const float* __restrict__ mean_b, const float* __restrict__ std_w,
    const float* __restrict__ std_b, const float* __restrict__ eps,
    const float* __restrict__ signal, float* __restrict__ prev_next,
    float* __restrict__ out_mean, float* __restrict__ out_logvar,
    float* __restrict__ out_tails) {
  int n = blockIdx.x;
  int tid = threadIdx.x;
  __shared__ float hv[F];
  __shared__ float red[8];
  if (tid < F) hv[tid] = __bfloat162float(H[(size_t)n * F + tid]);
  __syncthreads();
  const float* wr = pre_w + (size_t)tid * F;
  float s = pre_b[tid];
#pragma unroll
  for (int c = 0; c < F; ++c) s += hv[c] * wr[c];
  float p = fmaxf(s, 0.f);
  float m_c = p * mean_w[tid];
  float v_c = p * std_w[tid];
#pragma unroll
  for (int off = 32; off > 0; off >>= 1) {
    m_c += __shfl_down(m_c, off);
    v_c += __shfl_down(v_c, off);
  }
  int wid = tid >> 6;
  if ((tid & 63) == 0) { red[wid] = m_c; red[4 + wid] = v_c; }
  __syncthreads();
  if (tid == 0) {
    float mean = red[0] + red[1] + red[2] + red[3] + mean_b[0];
    float logv = red[4] + red[5] + red[6] + red[7] + std_b[0];
    float nx = eps[n] * expf(0.5f * logv) + mean;
    if (prev_next) prev_next[RFS + n] = nx;
    if (out_mean) { out_mean[n] = mean; out_logvar[n] = logv; }
    if (n >= NWIN - RFS) out_tails[n - (NWIN - RFS)] = nx;
  }
  if (tid == 1 && prev_next && n < RFS) prev_next[n] = signal[n];
}

// ---------------- host ----------------

extern "C" void kernel_launch(void* const* d_in, const int* in_sizes, int n_in,
                              void* d_out, int out_size, void* d_ws, size_t ws_size,
                              hipStream_t stream) {
  const float* mgc      = (const float*)d_in[0];
  const float* signal   = (const float*)d_in[1];
  const float* cond_w   = (const float*)d_in[2];
  const float* cond_b   = (const float*)d_in[3];
  const float* conv0_w  = (const float*)d_in[4];
  const float* conv0_b  = (const float*)d_in[5];
  const float* convL_w  = (const float*)d_in[6];
  const float* convL_b  = (const float*)d_in[7];
  const float* condlin_w= (const float*)d_in[8];
  const float* condlin_b= (const float*)d_in[9];
  const float* pre_w    = (const float*)d_in[10];
  const float* pre_b    = (const float*)d_in[11];
  const float* mean_w   = (const float*)d_in[12];
  const float* mean_b   = (const float*)d_in[13];
  const float* std_w    = (const float*)d_in[14];
  const float* std_b    = (const float*)d_in[15];
  const float* eps      = (const float*)d_in[16];
  float* out = (float*)d_out;

  float* wsf   = (float*)d_ws;
  float* cond  = wsf;                          // 48,000 f
  float* CI    = cond + 48000;                 // 7,372,800 f
  float* prevb = CI + 7372800;                 // 5,248 f
  float* base  = prevb + 5248;
  __hip_bfloat16* W2   = (__hip_bfloat16*)base;            // 3,145,728 bf16
  __hip_bfloat16* bufA = W2 + 3145728;                     // 26,214,400 + slack
  __hip_bfloat16* bufB = bufA + 26214400 + 65536;          // 13,107,200 + slack

  k_cond<<<(NWIN * MGCS + 255) / 256, 256, 0, stream>>>(mgc, cond_w, cond_b, cond);
  k_ci<<<72 * NWIN, 128, 0, stream>>>(cond, condlin_w, condlin_b, CI);
  k_wt<<<(NBLK * 8 * 384 * 256 + 255) / 256, 256, 0, stream>>>(convL_w, W2);
  k_outsig<<<(NWIN + 255) / 256, 256, 0, stream>>>(signal, out);

  for (int blk = 0; blk < NBLK; ++blk) {
    const float* prev = (blk == 0) ? signal : (prevb + (size_t)(blk - 1) * 1312);
    const float* CIb = CI + (size_t)(blk * NLAY) * 2 * NWIN * F;
    k_layer0<<<(NWIN * 256 * F + 255) / 256, 256, 0, stream>>>(
        prev, conv0_w + (size_t)blk * 3 * F * 2, conv0_b + (size_t)blk * 3 * F, CIb, bufA);

    __hip_bfloat16* cur = bufA;
    __hip_bfloat16* nxt = bufB;
    for (int l = 1; l < NLAY; ++l) {
      int Lout = 256 >> l;
      int M = NWIN * Lout;
      const float* ci0 = CI + ((size_t)((blk * NLAY + l) * 2 + 0)) * NWIN * F;
      const float* ci1 = CI + ((size_t)((blk * NLAY + l) * 2 + 1)) * NWIN * F;
      const __hip_bfloat16* wt = W2 + (size_t)(blk * 8 + (l - 1)) * 384 * 256;
      const float* bs = convL_b + (size_t)((blk * 8 + (l - 1)) * 3) * F;
      dim3 grid((M + 127) / 128);
      k_gemm<<<grid, 512, 0, stream>>>(cur, wt, bs, ci0, ci1, nxt, M, 8 - l);
      __hip_bfloat16* tmp = cur; cur = nxt; nxt = tmp;
    }
    k_head<<<NWIN, 256, 0, stream>>>(
        cur, pre_w + (size_t)blk * 256 * F, pre_b + (size_t)blk * 256,
        mean_w + (size_t)blk * 256, mean_b + blk,
        std_w + (size_t)blk * 256, std_b + blk,
        eps + (size_t)blk * NWIN, signal,
        (blk < 3) ? (prevb + (size_t)blk * 1312) : nullptr,
        (blk == 3) ? (out + 800) : nullptr,
        (blk == 3) ? (out + 1600) : nullptr,
        out + 2400 + (size_t)blk * 512);
  }
}

// Round 3
// 1306.854 us; speedup vs baseline: 2.6556x; 1.1784x over previous
//
#include <hip/hip_runtime.h>
#include <hip/hip_bf16.h>

#define F 128
#define MGCS 60
#define NWIN 800
#define RFS 512
#define NBLK 4
#define NLAY 9
#define SQF 0.70710678118f

typedef __attribute__((ext_vector_type(8))) short s16x8;
typedef __attribute__((ext_vector_type(4))) float f32x4;

__device__ __forceinline__ float fast_tanh(float x) {
  float e = __expf(2.f * x);
  return 1.f - 2.f / (e + 1.f);
}
__device__ __forceinline__ float fast_sig(float x) {
  return 1.f / (1.f + __expf(-x));
}

// ---------------- precompute kernels ----------------

__global__ void k_cond(const float* __restrict__ mgc, const float* __restrict__ cond_w,
                       const float* __restrict__ cond_b, float* __restrict__ cond) {
  int i = blockIdx.x * blockDim.x + threadIdx.x;
  if (i >= NWIN * MGCS) return;
  int n = i / MGCS, m = i % MGCS;
  int t = n / 200, u = n % 200;
  const float* wrow = cond_w + (size_t)(u * MGCS + m) * MGCS;
  const float* mr = mgc + t * MGCS;
  float s = cond_b[u * MGCS + m];
#pragma unroll
  for (int k = 0; k < MGCS; ++k) s += mr[k] * wrow[k];
  cond[i] = tanhf(s);
}

// CI[w][n][f]: tiled GEMM. grid (72, 7); 256 threads; 128n x 128f tile per block.
__global__ __launch_bounds__(256) void k_ci(
    const float* __restrict__ cond, const float* __restrict__ clw,
    const float* __restrict__ clb, float* __restrict__ CI) {
  int w = blockIdx.x;
  int n0 = blockIdx.y * 128;
  __shared__ float wsh[128][61];
  __shared__ float csh[128][61];
  int tid = threadIdx.x;
  for (int idx = tid; idx < 128 * MGCS; idx += 256) {
    int f = idx / MGCS, k = idx % MGCS;
    wsh[f][k] = clw[((size_t)w * 128 + f) * MGCS + k];
  }
  for (int idx = tid; idx < 128 * MGCS; idx += 256) {
    int n = idx / MGCS, k = idx % MGCS;
    csh[n][k] = (n0 + n < NWIN) ? cond[(n0 + n) * MGCS + k] : 0.f;
  }
  __syncthreads();
  int tn = tid >> 4, tf = tid & 15;
  float acc[8][8] = {};
  for (int k = 0; k < MGCS; ++k) {
    float a[8], b[8];
#pragma unroll
    for (int i = 0; i < 8; ++i) a[i] = csh[i * 16 + tn][k];
#pragma unroll
    for (int j = 0; j < 8; ++j) b[j] = wsh[j * 16 + tf][k];
#pragma unroll
    for (int i = 0; i < 8; ++i)
#pragma unroll
      for (int j = 0; j < 8; ++j) acc[i][j] += a[i] * b[j];
  }
  float bb[8];
#pragma unroll
  for (int j = 0; j < 8; ++j) bb[j] = clb[w * 128 + j * 16 + tf];
#pragma unroll
  for (int i = 0; i < 8; ++i) {
    int n = n0 + i * 16 + tn;
    if (n < NWIN) {
#pragma unroll
      for (int j = 0; j < 8; ++j)
        CI[((size_t)w * NWIN + n) * 128 + j * 16 + tf] = acc[i][j] + bb[j];
    }
  }
}

// W2[wl][tf][k] (bf16) = convL_w[blk][lm][t][f][c][k2], tf = t*128+f, k = k2*128+c
__global__ void k_wt(const float* __restrict__ convL_w, __hip_bfloat16* __restrict__ W2) {
  int i = blockIdx.x * blockDim.x + threadIdx.x;
  const int total = NBLK * 8 * 384 * 256;
  if (i >= total) return;
  int k = i & 255;
  int tf = (i >> 8) % 384;
  int wl = i / (384 * 256);
  int t = tf >> 7, f = tf & 127;
  int k2 = k >> 7, c = k & 127;
  W2[i] = __float2bfloat16(convL_w[(((size_t)(wl * 3 + t) * 128 + f) * 128 + c) * 2 + k2]);
}

__global__ void k_outsig(const float* __restrict__ signal, float* __restrict__ out) {
  int i = blockIdx.x * blockDim.x + threadIdx.x;
  if (i < NWIN) out[i] = signal[RFS + i];
}

// ---------------- per-block kernels ----------------

// layer 0 (Cin=1) fused with window gather; 8 f per thread, vector store.
__global__ void k_layer0(const float* __restrict__ prev, const float* __restrict__ w0,
                         const float* __restrict__ b0, const float* __restrict__ CIb,
                         __hip_bfloat16* __restrict__ out) {
  int i = blockIdx.x * blockDim.x + threadIdx.x;
  if (i >= NWIN * 256 * 16) return;
  int fg = i & 15;
  int rest = i >> 4;
  int j = rest & 255;
  int n = rest >> 8;
  int f0 = fg * 8;
  float x0 = prev[n + 2 * j], x1 = prev[n + 2 * j + 1];
  float4 ci0a = *(const float4*)(CIb + (size_t)n * F + f0);
  float4 ci0b = *(const float4*)(CIb + (size_t)n * F + f0 + 4);
  float4 ci1a = *(const float4*)(CIb + (size_t)NWIN * F + (size_t)n * F + f0);
  float4 ci1b = *(const float4*)(CIb + (size_t)NWIN * F + (size_t)n * F + f0 + 4);
  const float* ci0 = &ci0a.x;   // contiguous 8
  const float* ci1 = &ci1a.x;
  (void)ci0b; (void)ci1b;
  s16x8 res;
#pragma unroll
  for (int e = 0; e < 8; ++e) {
    int f = f0 + e;
    float c0 = (e < 4) ? (&ci0a.x)[e] : (&ci0b.x)[e - 4];
    float c1 = (e < 4) ? (&ci1a.x)[e] : (&ci1b.x)[e - 4];
    float o0 = b0[f]         + x0 * w0[(0 * F + f) * 2] + x1 * w0[(0 * F + f) * 2 + 1] + c0;
    float o1 = b0[F + f]     + x0 * w0[(1 * F + f) * 2] + x1 * w0[(1 * F + f) * 2 + 1] + c1;
    float o2 = b0[2 * F + f] + x0 * w0[(2 * F + f) * 2] + x1 * w0[(2 * F + f) * 2 + 1];
    __hip_bfloat16 h = __float2bfloat16((fast_tanh(o0) * fast_sig(o1) + o2) * SQF);
    res[e] = *(short*)&h;
  }
  *(s16x8*)(out + ((size_t)(n * 256 + j)) * F + f0) = res;
}

// MFMA GEMM: out[M][128] = act(A[M][256] x W2[384][256]^T + bias + CI)
// 512 threads = 8 waves (2m x 4f). BM = MFR*32. FS splits the 128 f-cols.
template <int MFR, int FS>
__global__ __launch_bounds__(512, 2) void k_gemm(
    const __hip_bfloat16* __restrict__ A, const __hip_bfloat16* __restrict__ W2,
    const float* __restrict__ bias, const float* __restrict__ CI0,
    const float* __restrict__ CI1, __hip_bfloat16* __restrict__ out,
    int M, int lgL) {
  constexpr int BM = MFR * 32;
  constexpr int FF = 2 / FS;                       // f-frags per gate per wave
  __shared__ char AsB[BM * 512];
  const int tid = threadIdx.x;
  const int lane = tid & 63, wid = tid >> 6;
  const int m0 = blockIdx.x * BM;
  const int f0 = blockIdx.y * (128 / FS);
  const char* Ab = (const char*)A + (size_t)m0 * 512;
  {
    const int half = lane >> 5;
    const int lin = (lane & 31) * 16;
#pragma unroll
    for (int it = 0; it < BM / 16; ++it) {
      int inst = wid * (BM / 16) + it;
      int row = inst * 2 + half;
      int src = row * 512 + (lin ^ ((row & 7) << 4));
      __builtin_amdgcn_global_load_lds(
          (const __attribute__((address_space(1))) unsigned int*)(Ab + src),
          (__attribute__((address_space(3))) unsigned int*)(AsB + inst * 1024), 16, 0, 0);
    }
  }
  __syncthreads();

  const int wm = wid & 1, wf = wid >> 1;
  const int col = lane & 15, kg = lane >> 4;
  f32x4 acc[MFR][FF][3];
#pragma unroll
  for (int mf = 0; mf < MFR; ++mf)
#pragma unroll
    for (int ff = 0; ff < FF; ++ff)
#pragma unroll
      for (int g = 0; g < 3; ++g) acc[mf][ff][g] = (f32x4)(0.f);

  const char* Wb = (const char*)W2;
#pragma unroll
  for (int ks = 0; ks < 8; ++ks) {
    s16x8 afr[MFR];
#pragma unroll
    for (int mf = 0; mf < MFR; ++mf) {
      int row = wm * (MFR * 16) + mf * 16 + col;
      int off = row * 512 + ((ks * 64 + kg * 16) ^ ((row & 7) << 4));
      afr[mf] = *(const s16x8*)(AsB + off);
    }
#pragma unroll
    for (int ff = 0; ff < FF; ++ff)
#pragma unroll
      for (int g = 0; g < 3; ++g) {
        int tf = g * 128 + f0 + wf * (FF * 16) + ff * 16 + col;
        s16x8 bfr = *(const s16x8*)(Wb + (size_t)tf * 512 + ks * 64 + kg * 16);
#pragma unroll
        for (int mf = 0; mf < MFR; ++mf)
          acc[mf][ff][g] =
              __builtin_amdgcn_mfma_f32_16x16x32_bf16(afr[mf], bfr, acc[mf][ff][g], 0, 0, 0);
      }
  }

#pragma unroll
  for (int mf = 0; mf < MFR; ++mf) {
    int mb = m0 + wm * (MFR * 16) + mf * 16 + kg * 4;
#pragma unroll
    for (int ff = 0; ff < FF; ++ff) {
      int f = f0 + wf * (FF * 16) + ff * 16 + col;
      float b0 = bias[f], b1 = bias[128 + f], b2 = bias[256 + f];
#pragma unroll
      for (int r = 0; r < 4; ++r) {
        int m = mb + r;
        if (m < M) {
          int n = m >> lgL;
          float o0 = acc[mf][ff][0][r] + b0 + CI0[n * 128 + f];
          float o1 = acc[mf][ff][1][r] + b1 + CI1[n * 128 + f];
          float o2 = acc[mf][ff][2][r] + b2;
          out[(size_t)m * 128 + f] =
              __float2bfloat16((fast_tanh(o0) * fast_sig(o1) + o2) * SQF);
        }
      }
    }
  }
}

// head: pre = relu(H @ pre_w^T + pre_b); mean/logvar; reparam; feedback + outputs
__global__ __launch_bounds__(256) void k_head(
    const __hip_bfloat16* __restrict__ H, const float* __restrict__ pre_w,
    const float* __restrict__ pre_b, const float* __restrict__ mean_w,
    const float* __restrict__ mean_b, const float* __restrict__ std_w,
    const float* __restrict__ std_b, const float* __restrict__ eps,
    const float* __restrict__ signal, float* __restrict__ prev_next,
    float* __restrict__ out_mean, float* __restrict__ out_logvar,
    float* __restrict__ out_tails) {
  int n = blockIdx.x;
  int tid = threadIdx.x;
  __shared__ float hv[F];
  __shared__ float red[8];
  if (tid < F) hv[tid] = __bfloat162float(H[(size_t)n * F + tid]);
  __syncthreads();
  const float* wr = pre_w + (size_t)tid * F;
  float s = pre_b[tid];
#pragma unroll
  for (int c = 0; c < F; ++c) s += hv[c] * wr[c];
  float p = fmaxf(s, 0.f);
  float m_c = p * mean_w[tid];
  float v_c = p * std_w[tid];
#pragma unroll
  for (int off = 32; off > 0; off >>= 1) {
    m_c += __shfl_down(m_c, off);
    v_c += __shfl_down(v_c, off);
  }
  int wid = tid >> 6;
  if ((tid & 63) == 0) { red[wid] = m_c; red[4 + wid] = v_c; }
  __syncthreads();
  if (tid == 0) {
    float mean = red[0] + red[1] + red[2] + red[3] + mean_b[0];
    float logv = red[4] + red[5] + red[6] + red[7] + std_b[0];
    float nx = eps[n] * expf(0.5f * logv) + mean;
    if (prev_next) prev_next[RFS + n] = nx;
    if (out_mean) { out_mean[n] = mean; out_logvar[n] = logv; }
    if (n >= NWIN - RFS) out_tails[n - (NWIN - RFS)] = nx;
  }
  if (tid == 1 && prev_next && n < RFS) prev_next[n] = signal[n];
}

// ---------------- host ----------------

extern "C" void kernel_launch(void* const* d_in, const int* in_sizes, int n_in,
                              void* d_out, int out_size, void* d_ws, size_t ws_size,
                              hipStream_t stream) {
  const float* mgc      = (const float*)d_in[0];
  const float* signal   = (const float*)d_in[1];
  const float* cond_w   = (const float*)d_in[2];
  const float* cond_b   = (const float*)d_in[3];
  const float* conv0_w  = (const float*)d_in[4];
  const float* conv0_b  = (const float*)d_in[5];
  const float* convL_w  = (const float*)d_in[6];
  const float* convL_b  = (const float*)d_in[7];
  const float* condlin_w= (const float*)d_in[8];
  const float* condlin_b= (const float*)d_in[9];
  const float* pre_w    = (const float*)d_in[10];
  const float* pre_b    = (const float*)d_in[11];
  const float* mean_w   = (const float*)d_in[12];
  const float* mean_b   = (const float*)d_in[13];
  const float* std_w    = (const float*)d_in[14];
  const float* std_b    = (const float*)d_in[15];
  const float* eps      = (const float*)d_in[16];
  float* out = (float*)d_out;

  float* wsf   = (float*)d_ws;
  float* cond  = wsf;                          // 48,000 f
  float* CI    = cond + 48000;                 // 7,372,800 f
  float* prevb = CI + 7372800;                 // 5,248 f
  float* base  = prevb + 5248;
  __hip_bfloat16* W2   = (__hip_bfloat16*)base;            // 3,145,728 bf16
  __hip_bfloat16* bufA = W2 + 3145728;                     // 26,214,400 + slack
  __hip_bfloat16* bufB = bufA + 26214400 + 65536;          // 13,107,200 + slack

  k_cond<<<(NWIN * MGCS + 255) / 256, 256, 0, stream>>>(mgc, cond_w, cond_b, cond);
  k_ci<<<dim3(72, 7), 256, 0, stream>>>(cond, condlin_w, condlin_b, CI);
  k_wt<<<(NBLK * 8 * 384 * 256 + 255) / 256, 256, 0, stream>>>(convL_w, W2);
  k_outsig<<<(NWIN + 255) / 256, 256, 0, stream>>>(signal, out);

  for (int blk = 0; blk < NBLK; ++blk) {
    const float* prev = (blk == 0) ? signal : (prevb + (size_t)(blk - 1) * 1312);
    const float* CIb = CI + (size_t)(blk * NLAY) * 2 * NWIN * F;
    k_layer0<<<(NWIN * 256 * 16 + 255) / 256, 256, 0, stream>>>(
        prev, conv0_w + (size_t)blk * 3 * F * 2, conv0_b + (size_t)blk * 3 * F, CIb, bufA);

    __hip_bfloat16* cur = bufA;
    __hip_bfloat16* nxt = bufB;
    for (int l = 1; l < NLAY; ++l) {
      int Lout = 256 >> l;
      int M = NWIN * Lout;
      const float* ci0 = CI + ((size_t)((blk * NLAY + l) * 2 + 0)) * NWIN * F;
      const float* ci1 = CI + ((size_t)((blk * NLAY + l) * 2 + 1)) * NWIN * F;
      const __hip_bfloat16* wt = W2 + (size_t)(blk * 8 + (l - 1)) * 384 * 256;
      const float* bs = convL_b + (size_t)((blk * 8 + (l - 1)) * 3) * F;
      if (l <= 2)
        k_gemm<4, 1><<<dim3(M / 128, 1), 512, 0, stream>>>(cur, wt, bs, ci0, ci1, nxt, M, 8 - l);
      else if (l <= 4)
        k_gemm<1, 1><<<dim3(M / 32, 1), 512, 0, stream>>>(cur, wt, bs, ci0, ci1, nxt, M, 8 - l);
      else
        k_gemm<1, 2><<<dim3(M / 32, 2), 512, 0, stream>>>(cur, wt, bs, ci0, ci1, nxt, M, 8 - l);
      __hip_bfloat16* tmp = cur; cur = nxt; nxt = tmp;
    }
    k_head<<<NWIN, 256, 0, stream>>>(
        cur, pre_w + (size_t)blk * 256 * F, pre_b + (size_t)blk * 256,
        mean_w + (size_t)blk * 256, mean_b + blk,
        std_w + (size_t)blk * 256, std_b + blk,
        eps + (size_t)blk * NWIN, signal,
        (blk < 3) ? (prevb + (size_t)blk * 1312) : nullptr,
        (blk == 3) ? (out + 800) : nullptr,
        (blk == 3) ? (out + 1600) : nullptr,
        out + 2400 + (size_t)blk * 512);
  }
}

// Round 4
// 978.651 us; speedup vs baseline: 3.5462x; 1.3354x over previous
//
#include <hip/hip_runtime.h>
#include <hip/hip_bf16.h>

#define F 128
#define MGCS 60
#define NWIN 800
#define RFS 512
#define NBLK 4
#define NLAY 9
#define SQF 0.70710678118f

typedef __attribute__((ext_vector_type(8))) short s16x8;
typedef __attribute__((ext_vector_type(4))) float f32x4;

#define VMCNT(n) asm volatile("s_waitcnt vmcnt(" #n ")" ::: "memory")

__device__ __forceinline__ float fast_tanh(float x) {
  float e = __expf(2.f * x);
  return 1.f - 2.f / (e + 1.f);
}
__device__ __forceinline__ float fast_sig(float x) {
  return 1.f / (1.f + __expf(-x));
}

// ---------------- precompute kernels ----------------

__global__ void k_cond(const float* __restrict__ mgc, const float* __restrict__ cond_w,
                       const float* __restrict__ cond_b, float* __restrict__ cond) {
  int i = blockIdx.x * blockDim.x + threadIdx.x;
  if (i >= NWIN * MGCS) return;
  int n = i / MGCS, m = i % MGCS;
  int t = n / 200, u = n % 200;
  const float* wrow = cond_w + (size_t)(u * MGCS + m) * MGCS;
  const float* mr = mgc + t * MGCS;
  float s = cond_b[u * MGCS + m];
#pragma unroll
  for (int k = 0; k < MGCS; ++k) s += mr[k] * wrow[k];
  cond[i] = tanhf(s);
}

// CI[w][n][f]: tiled GEMM. grid (72, 7); 256 threads; 128n x 128f tile per block.
__global__ __launch_bounds__(256) void k_ci(
    const float* __restrict__ cond, const float* __restrict__ clw,
    const float* __restrict__ clb, float* __restrict__ CI) {
  int w = blockIdx.x;
  int n0 = blockIdx.y * 128;
  __shared__ float wsh[128][61];
  __shared__ float csh[128][61];
  int tid = threadIdx.x;
  for (int idx = tid; idx < 128 * MGCS; idx += 256) {
    int f = idx / MGCS, k = idx % MGCS;
    wsh[f][k] = clw[((size_t)w * 128 + f) * MGCS + k];
  }
  for (int idx = tid; idx < 128 * MGCS; idx += 256) {
    int n = idx / MGCS, k = idx % MGCS;
    csh[n][k] = (n0 + n < NWIN) ? cond[(n0 + n) * MGCS + k] : 0.f;
  }
  __syncthreads();
  int tn = tid >> 4, tf = tid & 15;
  float acc[8][8] = {};
  for (int k = 0; k < MGCS; ++k) {
    float a[8], b[8];
#pragma unroll
    for (int i = 0; i < 8; ++i) a[i] = csh[i * 16 + tn][k];
#pragma unroll
    for (int j = 0; j < 8; ++j) b[j] = wsh[j * 16 + tf][k];
#pragma unroll
    for (int i = 0; i < 8; ++i)
#pragma unroll
      for (int j = 0; j < 8; ++j) acc[i][j] += a[i] * b[j];
  }
  float bb[8];
#pragma unroll
  for (int j = 0; j < 8; ++j) bb[j] = clb[w * 128 + j * 16 + tf];
#pragma unroll
  for (int i = 0; i < 8; ++i) {
    int n = n0 + i * 16 + tn;
    if (n < NWIN) {
#pragma unroll
      for (int j = 0; j < 8; ++j)
        CI[((size_t)w * NWIN + n) * 128 + j * 16 + tf] = acc[i][j] + bb[j];
    }
  }
}

// W2[wl][tf][k] (bf16) = convL_w[blk][lm][t][f][c][k2], tf = t*128+f, k = k2*128+c
__global__ void k_wt(const float* __restrict__ convL_w, __hip_bfloat16* __restrict__ W2) {
  int i = blockIdx.x * blockDim.x + threadIdx.x;
  const int total = NBLK * 8 * 384 * 256;
  if (i >= total) return;
  int k = i & 255;
  int tf = (i >> 8) % 384;
  int wl = i / (384 * 256);
  int t = tf >> 7, f = tf & 127;
  int k2 = k >> 7, c = k & 127;
  W2[i] = __float2bfloat16(convL_w[(((size_t)(wl * 3 + t) * 128 + f) * 128 + c) * 2 + k2]);
}

__global__ void k_outsig(const float* __restrict__ signal, float* __restrict__ out) {
  int i = blockIdx.x * blockDim.x + threadIdx.x;
  if (i < NWIN) out[i] = signal[RFS + i];
}

// ---------------- per-block kernels ----------------

// layer 0 (Cin=1) fused with window gather; 8 f per thread, vector store.
__global__ void k_layer0(const float* __restrict__ prev, const float* __restrict__ w0,
                         const float* __restrict__ b0, const float* __restrict__ CIb,
                         __hip_bfloat16* __restrict__ out) {
  int i = blockIdx.x * blockDim.x + threadIdx.x;
  if (i >= NWIN * 256 * 16) return;
  int fg = i & 15;
  int rest = i >> 4;
  int j = rest & 255;
  int n = rest >> 8;
  int f0 = fg * 8;
  float x0 = prev[n + 2 * j], x1 = prev[n + 2 * j + 1];
  float4 ci0a = *(const float4*)(CIb + (size_t)n * F + f0);
  float4 ci0b = *(const float4*)(CIb + (size_t)n * F + f0 + 4);
  float4 ci1a = *(const float4*)(CIb + (size_t)NWIN * F + (size_t)n * F + f0);
  float4 ci1b = *(const float4*)(CIb + (size_t)NWIN * F + (size_t)n * F + f0 + 4);
  s16x8 res;
#pragma unroll
  for (int e = 0; e < 8; ++e) {
    int f = f0 + e;
    float c0 = (e < 4) ? (&ci0a.x)[e] : (&ci0b.x)[e - 4];
    float c1 = (e < 4) ? (&ci1a.x)[e] : (&ci1b.x)[e - 4];
    float o0 = b0[f]         + x0 * w0[(0 * F + f) * 2] + x1 * w0[(0 * F + f) * 2 + 1] + c0;
    float o1 = b0[F + f]     + x0 * w0[(1 * F + f) * 2] + x1 * w0[(1 * F + f) * 2 + 1] + c1;
    float o2 = b0[2 * F + f] + x0 * w0[(2 * F + f) * 2] + x1 * w0[(2 * F + f) * 2 + 1];
    __hip_bfloat16 h = __float2bfloat16((fast_tanh(o0) * fast_sig(o1) + o2) * SQF);
    res[e] = *(short*)&h;
  }
  *(s16x8*)(out + ((size_t)(n * 256 + j)) * F + f0) = res;
}

// Weight-stationary persistent MFMA GEMM.
// out[M][128] = act(A[M][256] x W2[384][256]^T + bias + CI)
// 256 threads = 4 waves (one 16-f-col slice each); blockIdx.y = f-half (64 cols).
// B (24 frags) lives in registers for the block's lifetime; A tiles (BM=64)
// stream through a double-buffered LDS with counted vmcnt (never drained).
#define BM 64
__global__ __launch_bounds__(256, 2) void k_gemm(
    const __hip_bfloat16* __restrict__ A, const __hip_bfloat16* __restrict__ W2,
    const float* __restrict__ bias, const float* __restrict__ CI0,
    const float* __restrict__ CI1, __hip_bfloat16* __restrict__ out,
    int M, int lgL) {
  __shared__ char AsB[2][BM * 512];
  const int tid = threadIdx.x;
  const int lane = tid & 63, wid = tid >> 6;
  const int ntiles = (M + BM - 1) / BM;
  if ((int)blockIdx.x >= ntiles) return;
  const int fh = blockIdx.y;
  const int col = lane & 15, kg = lane >> 4;

  // ---- B into registers (once) ----
  const char* Wb = (const char*)W2;
  const int f = fh * 64 + wid * 16 + col;
  s16x8 breg[3][8];
#pragma unroll
  for (int g = 0; g < 3; ++g)
#pragma unroll
    for (int ks = 0; ks < 8; ++ks)
      breg[g][ks] = *(const s16x8*)(Wb + (size_t)(g * 128 + f) * 512 + ks * 64 + kg * 16);
  const float bz0 = bias[f], bz1 = bias[128 + f], bz2 = bias[256 + f];

  const char* Ab = (const char*)A;
  const int half = lane >> 5;
  const int lin = (lane & 31) * 16;
  // ---- prologue: stage tile blockIdx.x into buf0 ----
#pragma unroll
  for (int it = 0; it < 8; ++it) {
    int inst = wid * 8 + it;
    int row = inst * 2 + half;
    const char* src = Ab + (size_t)blockIdx.x * (BM * 512) + row * 512 + (lin ^ ((row & 7) << 6));
    __builtin_amdgcn_global_load_lds(
        (const __attribute__((address_space(1))) unsigned int*)src,
        (__attribute__((address_space(3))) unsigned int*)(&AsB[0][0] + inst * 1024), 16, 0, 0);
  }

  int cur = 0;
  for (int t = blockIdx.x; t < ntiles; t += gridDim.x) {
    int tn = t + gridDim.x;
    if (tn < ntiles) {
      char* dst = &AsB[cur ^ 1][0];
#pragma unroll
      for (int it = 0; it < 8; ++it) {
        int inst = wid * 8 + it;
        int row = inst * 2 + half;
        const char* src = Ab + (size_t)tn * (BM * 512) + row * 512 + (lin ^ ((row & 7) << 6));
        __builtin_amdgcn_global_load_lds(
            (const __attribute__((address_space(1))) unsigned int*)src,
            (__attribute__((address_space(3))) unsigned int*)(dst + inst * 1024), 16, 0, 0);
      }
      VMCNT(8);            // current tile's 8 loads done; next tile's stay in flight
    } else {
      VMCNT(0);
    }
    __builtin_amdgcn_s_barrier();
    __builtin_amdgcn_sched_barrier(0);

    f32x4 acc[4][3];
#pragma unroll
    for (int mf = 0; mf < 4; ++mf)
#pragma unroll
      for (int g = 0; g < 3; ++g) acc[mf][g] = (f32x4)(0.f);

    const char* buf = &AsB[cur][0];
    __builtin_amdgcn_s_setprio(1);
#pragma unroll
    for (int ks = 0; ks < 8; ++ks) {
      s16x8 afr[4];
#pragma unroll
      for (int mf = 0; mf < 4; ++mf) {
        int row = mf * 16 + col;
        afr[mf] = *(const s16x8*)(buf + row * 512 + ((ks * 64 + kg * 16) ^ ((row & 7) << 6)));
      }
#pragma unroll
      for (int g = 0; g < 3; ++g)
#pragma unroll
        for (int mf = 0; mf < 4; ++mf)
          acc[mf][g] = __builtin_amdgcn_mfma_f32_16x16x32_bf16(afr[mf], breg[g][ks], acc[mf][g], 0, 0, 0);
    }
    __builtin_amdgcn_s_setprio(0);

    // epilogue
    int m0 = t * BM;
#pragma unroll
    for (int mf = 0; mf < 4; ++mf) {
      int mb = m0 + mf * 16 + kg * 4;
#pragma unroll
      for (int r = 0; r < 4; ++r) {
        int m = mb + r;
        if (m < M) {
          int n = m >> lgL;
          float o0 = acc[mf][0][r] + bz0 + CI0[n * 128 + f];
          float o1 = acc[mf][1][r] + bz1 + CI1[n * 128 + f];
          float o2 = acc[mf][2][r] + bz2;
          out[(size_t)m * 128 + f] =
              __float2bfloat16((fast_tanh(o0) * fast_sig(o1) + o2) * SQF);
        }
      }
    }
    __builtin_amdgcn_s_barrier();   // all waves done reading buf before it's restaged
    cur ^= 1;
  }
}

// head: pre = relu(H @ pre_w^T + pre_b); mean/logvar; reparam; feedback + outputs
__global__ __launch_bounds__(256) void k_head(
    const __hip_bfloat16* __restrict__ H, const float* __restrict__ pre_w,
    const float* __restrict__ pre_b, const float* __restrict__ mean_w,
    const float* __restrict__ mean_b, const float* __restrict__ std_w,
    const float* __restrict__ std_b, const float* __restrict__ eps,
    const float* __restrict__ signal, float* __restrict__ prev_next,
    float* __restrict__ out_mean, float* __restrict__ out_logvar,
    float* __restrict__ out_tails) {
  int n = blockIdx.x;
  int tid = threadIdx.x;
  __shared__ float hv[F];
  __shared__ float red[8];
  if (tid < F) hv[tid] = __bfloat162float(H[(size_t)n * F + tid]);
  __syncthreads();
  const float* wr = pre_w + (size_t)tid * F;
  float s = pre_b[tid];
#pragma unroll
  for (int c = 0; c < F; ++c) s += hv[c] * wr[c];
  float p = fmaxf(s, 0.f);
  float m_c = p * mean_w[tid];
  float v_c = p * std_w[tid];
#pragma unroll
  for (int off = 32; off > 0; off >>= 1) {
    m_c += __shfl_down(m_c, off);
    v_c += __shfl_down(v_c, off);
  }
  int wid = tid >> 6;
  if ((tid & 63) == 0) { red[wid] = m_c; red[4 + wid] = v_c; }
  __syncthreads();
  if (tid == 0) {
    float mean = red[0] + red[1] + red[2] + red[3] + mean_b[0];
    float logv = red[4] + red[5] + red[6] + red[7] + std_b[0];
    float nx = eps[n] * expf(0.5f * logv) + mean;
    if (prev_next) prev_next[RFS + n] = nx;
    if (out_mean) { out_mean[n] = mean; out_logvar[n] = logv; }
    if (n >= NWIN - RFS) out_tails[n - (NWIN - RFS)] = nx;
  }
  if (tid == 1 && prev_next && n < RFS) prev_next[n] = signal[n];
}

// ---------------- host ----------------

extern "C" void kernel_launch(void* const* d_in, const int* in_sizes, int n_in,
                              void* d_out, int out_size, void* d_ws, size_t ws_size,
                              hipStream_t stream) {
  const float* mgc      = (const float*)d_in[0];
  const float* signal   = (const float*)d_in[1];
  const float* cond_w   = (const float*)d_in[2];
  const float* cond_b   = (const float*)d_in[3];
  const float* conv0_w  = (const float*)d_in[4];
  const float* conv0_b  = (const float*)d_in[5];
  const float* convL_w  = (const float*)d_in[6];
  const float* convL_b  = (const float*)d_in[7];
  const float* condlin_w= (const float*)d_in[8];
  const float* condlin_b= (const float*)d_in[9];
  const float* pre_w    = (const float*)d_in[10];
  const float* pre_b    = (const float*)d_in[11];
  const float* mean_w   = (const float*)d_in[12];
  const float* mean_b   = (const float*)d_in[13];
  const float* std_w    = (const float*)d_in[14];
  const float* std_b    = (const float*)d_in[15];
  const float* eps      = (const float*)d_in[16];
  float* out = (float*)d_out;

  float* wsf   = (float*)d_ws;
  float* cond  = wsf;                          // 48,000 f
  float* CI    = cond + 48000;                 // 7,372,800 f
  float* prevb = CI + 7372800;                 // 5,248 f
  float* base  = prevb + 5248;
  __hip_bfloat16* W2   = (__hip_bfloat16*)base;            // 3,145,728 bf16
  __hip_bfloat16* bufA = W2 + 3145728;                     // 26,214,400 + slack
  __hip_bfloat16* bufB = bufA + 26214400 + 65536;          // 13,107,200 + slack

  k_cond<<<(NWIN * MGCS + 255) / 256, 256, 0, stream>>>(mgc, cond_w, cond_b, cond);
  k_ci<<<dim3(72, 7), 256, 0, stream>>>(cond, condlin_w, condlin_b, CI);
  k_wt<<<(NBLK * 8 * 384 * 256 + 255) / 256, 256, 0, stream>>>(convL_w, W2);
  k_outsig<<<(NWIN + 255) / 256, 256, 0, stream>>>(signal, out);

  for (int blk = 0; blk < NBLK; ++blk) {
    const float* prev = (blk == 0) ? signal : (prevb + (size_t)(blk - 1) * 1312);
    const float* CIb = CI + (size_t)(blk * NLAY) * 2 * NWIN * F;
    k_layer0<<<(NWIN * 256 * 16 + 255) / 256, 256, 0, stream>>>(
        prev, conv0_w + (size_t)blk * 3 * F * 2, conv0_b + (size_t)blk * 3 * F, CIb, bufA);

    __hip_bfloat16* cur = bufA;
    __hip_bfloat16* nxt = bufB;
    for (int l = 1; l < NLAY; ++l) {
      int Lout = 256 >> l;
      int M = NWIN * Lout;
      const float* ci0 = CI + ((size_t)((blk * NLAY + l) * 2 + 0)) * NWIN * F;
      const float* ci1 = CI + ((size_t)((blk * NLAY + l) * 2 + 1)) * NWIN * F;
      const __hip_bfloat16* wt = W2 + (size_t)(blk * 8 + (l - 1)) * 384 * 256;
      const float* bs = convL_b + (size_t)((blk * 8 + (l - 1)) * 3) * F;
      int ntiles = (M + BM - 1) / BM;
      int gx = ntiles < 256 ? ((ntiles + 7) & ~7) : 256;
      k_gemm<<<dim3(gx, 2), 256, 0, stream>>>(cur, wt, bs, ci0, ci1, nxt, M, 8 - l);
      __hip_bfloat16* tmp = cur; cur = nxt; nxt = tmp;
    }
    k_head<<<NWIN, 256, 0, stream>>>(
        cur, pre_w + (size_t)blk * 256 * F, pre_b + (size_t)blk * 256,
        mean_w + (size_t)blk * 256, mean_b + blk,
        std_w + (size_t)blk * 256, std_b + blk,
        eps + (size_t)blk * NWIN, signal,
        (blk < 3) ? (prevb + (size_t)blk * 1312) : nullptr,
        (blk == 3) ? (out + 800) : nullptr,
        (blk == 3) ? (out + 1600) : nullptr,
        out + 2400 + (size_t)blk * 512);
  }
}

// Round 5
// 957.364 us; speedup vs baseline: 3.6251x; 1.0222x over previous
//
#include <hip/hip_runtime.h>
#include <hip/hip_bf16.h>

#define F 128
#define MGCS 60
#define NWIN 800
#define RFS 512
#define NBLK 4
#define NLAY 9
#define SQF 0.70710678118f

typedef __attribute__((ext_vector_type(8))) short s16x8;
typedef __attribute__((ext_vector_type(4))) float f32x4;

#define VMCNT(n) asm volatile("s_waitcnt vmcnt(" #n ")" ::: "memory")

// combined tanh(o0)*sigmoid(o1) + o2, 2 exp + 1 rcp.
// clamp keeps every intermediate finite; tanh/sig are saturated at |21| anyway.
__device__ __forceinline__ float gated_act(float o0, float o1, float o2) {
  o0 = fminf(fmaxf(o0, -21.f), 21.f);
  o1 = fminf(fmaxf(o1, -21.f), 21.f);
  float a = __expf(2.f * o0);
  float b = __expf(-o1);
  float r = (a - 1.f) * __builtin_amdgcn_rcpf((a + 1.f) * (1.f + b));
  return (r + o2) * SQF;
}

// ---------------- precompute kernels ----------------

__global__ void k_cond(const float* __restrict__ mgc, const float* __restrict__ cond_w,
                       const float* __restrict__ cond_b, float* __restrict__ cond) {
  int i = blockIdx.x * blockDim.x + threadIdx.x;
  if (i >= NWIN * MGCS) return;
  int n = i / MGCS, m = i % MGCS;
  int t = n / 200, u = n % 200;
  const float* wrow = cond_w + (size_t)(u * MGCS + m) * MGCS;
  const float* mr = mgc + t * MGCS;
  float s = cond_b[u * MGCS + m];
#pragma unroll
  for (int k = 0; k < MGCS; ++k) s += mr[k] * wrow[k];
  cond[i] = tanhf(s);
}

// CI[w][n][f]: tiled GEMM. grid (72, 7); 256 threads; 128n x 128f tile per block.
__global__ __launch_bounds__(256) void k_ci(
    const float* __restrict__ cond, const float* __restrict__ clw,
    const float* __restrict__ clb, float* __restrict__ CI) {
  int w = blockIdx.x;
  int n0 = blockIdx.y * 128;
  __shared__ float wsh[128][61];
  __shared__ float csh[128][61];
  int tid = threadIdx.x;
  for (int idx = tid; idx < 128 * MGCS; idx += 256) {
    int f = idx / MGCS, k = idx % MGCS;
    wsh[f][k] = clw[((size_t)w * 128 + f) * MGCS + k];
  }
  for (int idx = tid; idx < 128 * MGCS; idx += 256) {
    int n = idx / MGCS, k = idx % MGCS;
    csh[n][k] = (n0 + n < NWIN) ? cond[(n0 + n) * MGCS + k] : 0.f;
  }
  __syncthreads();
  int tn = tid >> 4, tf = tid & 15;
  float acc[8][8] = {};
  for (int k = 0; k < MGCS; ++k) {
    float a[8], b[8];
#pragma unroll
    for (int i = 0; i < 8; ++i) a[i] = csh[i * 16 + tn][k];
#pragma unroll
    for (int j = 0; j < 8; ++j) b[j] = wsh[j * 16 + tf][k];
#pragma unroll
    for (int i = 0; i < 8; ++i)
#pragma unroll
      for (int j = 0; j < 8; ++j) acc[i][j] += a[i] * b[j];
  }
  float bb[8];
#pragma unroll
  for (int j = 0; j < 8; ++j) bb[j] = clb[w * 128 + j * 16 + tf];
#pragma unroll
  for (int i = 0; i < 8; ++i) {
    int n = n0 + i * 16 + tn;
    if (n < NWIN) {
#pragma unroll
      for (int j = 0; j < 8; ++j)
        CI[((size_t)w * NWIN + n) * 128 + j * 16 + tf] = acc[i][j] + bb[j];
    }
  }
}

// W2[wl][tf][k] (bf16) = convL_w[blk][lm][t][f][c][k2], tf = t*128+f, k = k2*128+c
__global__ void k_wt(const float* __restrict__ convL_w, __hip_bfloat16* __restrict__ W2) {
  int i = blockIdx.x * blockDim.x + threadIdx.x;
  const int total = NBLK * 8 * 384 * 256;
  if (i >= total) return;
  int k = i & 255;
  int tf = (i >> 8) % 384;
  int wl = i / (384 * 256);
  int t = tf >> 7, f = tf & 127;
  int k2 = k >> 7, c = k & 127;
  W2[i] = __float2bfloat16(convL_w[(((size_t)(wl * 3 + t) * 128 + f) * 128 + c) * 2 + k2]);
}

__global__ void k_outsig(const float* __restrict__ signal, float* __restrict__ out) {
  int i = blockIdx.x * blockDim.x + threadIdx.x;
  if (i < NWIN) out[i] = signal[RFS + i];
}

// ---------------- per-block kernels ----------------

// CV[s][tf] = b0[tf] + prev[s]*w0[tf][0] + prev[s+1]*w0[tf][1], s in [0,1310)
__global__ void k_pre0(const float* __restrict__ prev, const float* __restrict__ w0,
                       const float* __restrict__ b0, float* __restrict__ CV) {
  int i = blockIdx.x * blockDim.x + threadIdx.x;
  if (i >= 1310 * 384) return;
  int tf = i % 384, s = i / 384;
  CV[i] = b0[tf] + prev[s] * w0[tf * 2] + prev[s + 1] * w0[tf * 2 + 1];
}

// layer 0: out[n][j][f] = act(CV[n+2j][f..] + CI(n)), 8 f per thread.
__global__ void k_layer0(const float* __restrict__ CV, const float* __restrict__ CIb,
                         __hip_bfloat16* __restrict__ out) {
  int i = blockIdx.x * blockDim.x + threadIdx.x;
  if (i >= NWIN * 256 * 16) return;
  int fg = i & 15;
  int rest = i >> 4;
  int j = rest & 255;
  int n = rest >> 8;
  int f0 = fg * 8;
  const float* cv = CV + (size_t)(n + 2 * j) * 384;
  const float* ci = CIb + (size_t)n * F;
  float4 c0a = *(const float4*)(cv + f0),       c0b = *(const float4*)(cv + f0 + 4);
  float4 c1a = *(const float4*)(cv + 128 + f0), c1b = *(const float4*)(cv + 132 + f0);
  float4 c2a = *(const float4*)(cv + 256 + f0), c2b = *(const float4*)(cv + 260 + f0);
  float4 i0a = *(const float4*)(ci + f0),       i0b = *(const float4*)(ci + f0 + 4);
  float4 i1a = *(const float4*)(ci + (size_t)NWIN * F + f0);
  float4 i1b = *(const float4*)(ci + (size_t)NWIN * F + f0 + 4);
  s16x8 res;
#pragma unroll
  for (int e = 0; e < 8; ++e) {
    float o0 = ((e < 4) ? (&c0a.x)[e] : (&c0b.x)[e - 4]) + ((e < 4) ? (&i0a.x)[e] : (&i0b.x)[e - 4]);
    float o1 = ((e < 4) ? (&c1a.x)[e] : (&c1b.x)[e - 4]) + ((e < 4) ? (&i1a.x)[e] : (&i1b.x)[e - 4]);
    float o2 = (e < 4) ? (&c2a.x)[e] : (&c2b.x)[e - 4];
    __hip_bfloat16 h = __float2bfloat16(gated_act(o0, o1, o2));
    res[e] = *(short*)&h;
  }
  *(s16x8*)(out + ((size_t)(n * 256 + j)) * F + f0) = res;
}

// Weight-stationary persistent MFMA GEMM, 512 threads = 8 waves, each wave owns
// 16 of the 128 f-cols (all 3 gates in regs: 96 VGPR). A tiles (BM=64) stream
// through double-buffered LDS via global_load_lds, counted vmcnt (never 0 mid-loop).
#define BM 64
__global__ __launch_bounds__(512, 2) void k_gemm(
    const __hip_bfloat16* __restrict__ A, const __hip_bfloat16* __restrict__ W2,
    const float* __restrict__ bias, const float* __restrict__ CI0,
    const float* __restrict__ CI1, __hip_bfloat16* __restrict__ out,
    int M, int lgL) {
  __shared__ char AsB[2][BM * 512];               // 2 x 32 KB
  const int tid = threadIdx.x;
  const int lane = tid & 63, wid = tid >> 6;
  const int ntiles = (M + BM - 1) / BM;
  const int gdx = gridDim.x;
  const int col = lane & 15, kg = lane >> 4;

  // ---- B into registers (once) ----
  const char* Wb = (const char*)W2;
  const int f = wid * 16 + col;
  s16x8 breg[3][8];
#pragma unroll
  for (int g = 0; g < 3; ++g)
#pragma unroll
    for (int ks = 0; ks < 8; ++ks)
      breg[g][ks] = *(const s16x8*)(Wb + (size_t)(g * 128 + f) * 512 + ks * 64 + kg * 16);
  const float bz0 = bias[f], bz1 = bias[128 + f], bz2 = bias[256 + f];

  const char* Ab = (const char*)A;
  const int half = lane >> 5;
  const int lin = (lane & 31) * 16;
  // ---- prologue: stage first tile into buf0 (4 insts per thread-wave) ----
#pragma unroll
  for (int it = 0; it < 4; ++it) {
    int inst = wid * 4 + it;
    int row = inst * 2 + half;
    const char* src = Ab + (size_t)blockIdx.x * (BM * 512) + row * 512 + (lin ^ ((row & 7) << 4));
    __builtin_amdgcn_global_load_lds(
        (const __attribute__((address_space(1))) unsigned int*)src,
        (__attribute__((address_space(3))) unsigned int*)(&AsB[0][0] + inst * 1024), 16, 0, 0);
  }

  int cur = 0;
  for (int t = blockIdx.x; t < ntiles; t += gdx) {
    int tn = t + gdx;
    if (tn < ntiles) {
      char* dst = &AsB[cur ^ 1][0];
#pragma unroll
      for (int it = 0; it < 4; ++it) {
        int inst = wid * 4 + it;
        int row = inst * 2 + half;
        const char* src = Ab + (size_t)tn * (BM * 512) + row * 512 + (lin ^ ((row & 7) << 4));
        __builtin_amdgcn_global_load_lds(
            (const __attribute__((address_space(1))) unsigned int*)src,
            (__attribute__((address_space(3))) unsigned int*)(dst + inst * 1024), 16, 0, 0);
      }
      VMCNT(4);            // current tile's loads done; next tile's 4 stay in flight
    } else {
      VMCNT(0);
    }
    __builtin_amdgcn_s_barrier();
    __builtin_amdgcn_sched_barrier(0);

    f32x4 acc[4][3];
#pragma unroll
    for (int mf = 0; mf < 4; ++mf)
#pragma unroll
      for (int g = 0; g < 3; ++g) acc[mf][g] = (f32x4)(0.f);

    const char* buf = &AsB[cur][0];
    __builtin_amdgcn_s_setprio(1);
#pragma unroll
    for (int ks = 0; ks < 8; ++ks) {
      s16x8 afr[4];
#pragma unroll
      for (int mf = 0; mf < 4; ++mf) {
        int row = mf * 16 + col;
        afr[mf] = *(const s16x8*)(buf + row * 512 + ((ks * 64 + kg * 16) ^ ((row & 7) << 4)));
      }
#pragma unroll
      for (int g = 0; g < 3; ++g)
#pragma unroll
        for (int mf = 0; mf < 4; ++mf)
          acc[mf][g] = __builtin_amdgcn_mfma_f32_16x16x32_bf16(afr[mf], breg[g][ks], acc[mf][g], 0, 0, 0);
    }
    __builtin_amdgcn_s_setprio(0);

    // epilogue
    int m0 = t * BM;
#pragma unroll
    for (int mf = 0; mf < 4; ++mf) {
      int mb = m0 + mf * 16 + kg * 4;
#pragma unroll
      for (int r = 0; r < 4; ++r) {
        int m = mb + r;
        if (m < M) {
          int n = m >> lgL;
          float o0 = acc[mf][0][r] + bz0 + CI0[n * 128 + f];
          float o1 = acc[mf][1][r] + bz1 + CI1[n * 128 + f];
          float o2 = acc[mf][2][r] + bz2;
          out[(size_t)m * 128 + f] = __float2bfloat16(gated_act(o0, o1, o2));
        }
      }
    }
    __builtin_amdgcn_s_barrier();   // all waves done reading buf before restage
    cur ^= 1;
  }
}

// head: pre = relu(H @ pre_w^T + pre_b); mean/logvar; reparam; feedback + outputs
__global__ __launch_bounds__(256) void k_head(
    const __hip_bfloat16* __restrict__ H, const float* __restrict__ pre_w,
    const float* __restrict__ pre_b, const float* __restrict__ mean_w,
    const float* __restrict__ mean_b, const float* __restrict__ std_w,
    const float* __restrict__ std_b, const float* __restrict__ eps,
    const float* __restrict__ signal, float* __restrict__ prev_next,
    float* __restrict__ out_mean, float* __restrict__ out_logvar,
    float* __restrict__ out_tails) {
  int n = blockIdx.x;
  int tid = threadIdx.x;
  __shared__ float hv[F];
  __shared__ float red[8];
  if (tid < F) hv[tid] = __bfloat162float(H[(size_t)n * F + tid]);
  __syncthreads();
  const float* wr = pre_w + (size_t)tid * F;
  float s = pre_b[tid];
#pragma unroll
  for (int c = 0; c < F; ++c) s += hv[c] * wr[c];
  float p = fmaxf(s, 0.f);
  float m_c = p * mean_w[tid];
  float v_c = p * std_w[tid];
#pragma unroll
  for (int off = 32; off > 0; off >>= 1) {
    m_c += __shfl_down(m_c, off);
    v_c += __shfl_down(v_c, off);
  }
  int wid = tid >> 6;
  if ((tid & 63) == 0) { red[wid] = m_c; red[4 + wid] = v_c; }
  __syncthreads();
  if (tid == 0) {
    float mean = red[0] + red[1] + red[2] + red[3] + mean_b[0];
    float logv = red[4] + red[5] + red[6] + red[7] + std_b[0];
    float nx = eps[n] * expf(0.5f * logv) + mean;
    if (prev_next) prev_next[RFS + n] = nx;
    if (out_mean) { out_mean[n] = mean; out_logvar[n] = logv; }
    if (n >= NWIN - RFS) out_tails[n - (NWIN - RFS)] = nx;
  }
  if (tid == 1 && prev_next && n < RFS) prev_next[n] = signal[n];
}

// ---------------- host ----------------

extern "C" void kernel_launch(void* const* d_in, const int* in_sizes, int n_in,
                              void* d_out, int out_size, void* d_ws, size_t ws_size,
                              hipStream_t stream) {
  const float* mgc      = (const float*)d_in[0];
  const float* signal   = (const float*)d_in[1];
  const float* cond_w   = (const float*)d_in[2];
  const float* cond_b   = (const float*)d_in[3];
  const float* conv0_w  = (const float*)d_in[4];
  const float* conv0_b  = (const float*)d_in[5];
  const float* convL_w  = (const float*)d_in[6];
  const float* convL_b  = (const float*)d_in[7];
  const float* condlin_w= (const float*)d_in[8];
  const float* condlin_b= (const float*)d_in[9];
  const float* pre_w    = (const float*)d_in[10];
  const float* pre_b    = (const float*)d_in[11];
  const float* mean_w   = (const float*)d_in[12];
  const float* mean_b   = (const float*)d_in[13];
  const float* std_w    = (const float*)d_in[14];
  const float* std_b    = (const float*)d_in[15];
  const float* eps      = (const float*)d_in[16];
  float* out = (float*)d_out;

  float* wsf   = (float*)d_ws;
  float* cond  = wsf;                          // 48,000 f
  float* CI    = cond + 48000;                 // 7,372,800 f
  float* prevb = CI + 7372800;                 // 5,248 f
  float* CV    = prevb + 5248;                 // 1310*384 = 503,040 f
  float* base  = CV + 503040;
  __hip_bfloat16* W2   = (__hip_bfloat16*)base;            // 3,145,728 bf16
  __hip_bfloat16* bufA = W2 + 3145728;                     // 26,214,400 + slack
  __hip_bfloat16* bufB = bufA + 26214400 + 65536;          // 13,107,200 + slack

  k_cond<<<(NWIN * MGCS + 255) / 256, 256, 0, stream>>>(mgc, cond_w, cond_b, cond);
  k_ci<<<dim3(72, 7), 256, 0, stream>>>(cond, condlin_w, condlin_b, CI);
  k_wt<<<(NBLK * 8 * 384 * 256 + 255) / 256, 256, 0, stream>>>(convL_w, W2);
  k_outsig<<<(NWIN + 255) / 256, 256, 0, stream>>>(signal, out);

  for (int blk = 0; blk < NBLK; ++blk) {
    const float* prev = (blk == 0) ? signal : (prevb + (size_t)(blk - 1) * 1312);
    const float* CIb = CI + (size_t)(blk * NLAY) * 2 * NWIN * F;
    k_pre0<<<(1310 * 384 + 255) / 256, 256, 0, stream>>>(
        prev, conv0_w + (size_t)blk * 3 * F * 2, conv0_b + (size_t)blk * 3 * F, CV);
    k_layer0<<<(NWIN * 256 * 16 + 255) / 256, 256, 0, stream>>>(CV, CIb, bufA);

    __hip_bfloat16* cur = bufA;
    __hip_bfloat16* nxt = bufB;
    for (int l = 1; l < NLAY; ++l) {
      int Lout = 256 >> l;
      int M = NWIN * Lout;
      const float* ci0 = CI + ((size_t)((blk * NLAY + l) * 2 + 0)) * NWIN * F;
      const float* ci1 = CI + ((size_t)((blk * NLAY + l) * 2 + 1)) * NWIN * F;
      const __hip_bfloat16* wt = W2 + (size_t)(blk * 8 + (l - 1)) * 384 * 256;
      const float* bs = convL_b + (size_t)((blk * 8 + (l - 1)) * 3) * F;
      int ntiles = (M + BM - 1) / BM;
      int gx = ntiles < 512 ? ntiles : 512;
      k_gemm<<<dim3(gx), 512, 0, stream>>>(cur, wt, bs, ci0, ci1, nxt, M, 8 - l);
      __hip_bfloat16* tmp = cur; cur = nxt; nxt = tmp;
    }
    k_head<<<NWIN, 256, 0, stream>>>(
        cur, pre_w + (size_t)blk * 256 * F, pre_b + (size_t)blk * 256,
        mean_w + (size_t)blk * 256, mean_b + blk,
        std_w + (size_t)blk * 256, std_b + blk,
        eps + (size_t)blk * NWIN, signal,
        (blk < 3) ? (prevb + (size_t)blk * 1312) : nullptr,
        (blk == 3) ? (out + 800) : nullptr,
        (blk == 3) ? (out + 1600) : nullptr,
        out + 2400 + (size_t)blk * 512);
  }
}

// Round 6
// 805.184 us; speedup vs baseline: 4.3102x; 1.1890x over previous
//
#include <hip/hip_runtime.h>
#include <hip/hip_bf16.h>

#define F 128
#define MGCS 60
#define NWIN 800
#define RFS 512
#define NBLK 4
#define NLAY 9
#define SQF 0.70710678118f

typedef __attribute__((ext_vector_type(8))) short s16x8;
typedef __attribute__((ext_vector_type(4))) float f32x4;

#define VMCNT(n) asm volatile("s_waitcnt vmcnt(" #n ")" ::: "memory")

// combined tanh(o0)*sigmoid(o1) + o2, 2 exp + 1 rcp.
__device__ __forceinline__ float gated_act(float o0, float o1, float o2) {
  o0 = fminf(fmaxf(o0, -21.f), 21.f);
  o1 = fminf(fmaxf(o1, -21.f), 21.f);
  float a = __expf(2.f * o0);
  float b = __expf(-o1);
  float r = (a - 1.f) * __builtin_amdgcn_rcpf((a + 1.f) * (1.f + b));
  return (r + o2) * SQF;
}

// ---------------- precompute kernels ----------------

__global__ void k_cond(const float* __restrict__ mgc, const float* __restrict__ cond_w,
                       const float* __restrict__ cond_b, float* __restrict__ cond) {
  int i = blockIdx.x * blockDim.x + threadIdx.x;
  if (i >= NWIN * MGCS) return;
  int n = i / MGCS, m = i % MGCS;
  int t = n / 200, u = n % 200;
  const float* wrow = cond_w + (size_t)(u * MGCS + m) * MGCS;
  const float* mr = mgc + t * MGCS;
  float s = cond_b[u * MGCS + m];
#pragma unroll
  for (int k = 0; k < MGCS; ++k) s += mr[k] * wrow[k];
  cond[i] = tanhf(s);
}

// CI[w][n][f]: tiled GEMM. grid (72, 7); 256 threads; 128n x 128f tile per block.
__global__ __launch_bounds__(256) void k_ci(
    const float* __restrict__ cond, const float* __restrict__ clw,
    const float* __restrict__ clb, float* __restrict__ CI) {
  int w = blockIdx.x;
  int n0 = blockIdx.y * 128;
  __shared__ float wsh[128][61];
  __shared__ float csh[128][61];
  int tid = threadIdx.x;
  for (int idx = tid; idx < 128 * MGCS; idx += 256) {
    int f = idx / MGCS, k = idx % MGCS;
    wsh[f][k] = clw[((size_t)w * 128 + f) * MGCS + k];
  }
  for (int idx = tid; idx < 128 * MGCS; idx += 256) {
    int n = idx / MGCS, k = idx % MGCS;
    csh[n][k] = (n0 + n < NWIN) ? cond[(n0 + n) * MGCS + k] : 0.f;
  }
  __syncthreads();
  int tn = tid >> 4, tf = tid & 15;
  float acc[8][8] = {};
  for (int k = 0; k < MGCS; ++k) {
    float a[8], b[8];
#pragma unroll
    for (int i = 0; i < 8; ++i) a[i] = csh[i * 16 + tn][k];
#pragma unroll
    for (int j = 0; j < 8; ++j) b[j] = wsh[j * 16 + tf][k];
#pragma unroll
    for (int i = 0; i < 8; ++i)
#pragma unroll
      for (int j = 0; j < 8; ++j) acc[i][j] += a[i] * b[j];
  }
  float bb[8];
#pragma unroll
  for (int j = 0; j < 8; ++j) bb[j] = clb[w * 128 + j * 16 + tf];
#pragma unroll
  for (int i = 0; i < 8; ++i) {
    int n = n0 + i * 16 + tn;
    if (n < NWIN) {
#pragma unroll
      for (int j = 0; j < 8; ++j)
        CI[((size_t)w * NWIN + n) * 128 + j * 16 + tf] = acc[i][j] + bb[j];
    }
  }
}

// W2[wl][tf][k] (bf16) = convL_w[blk][lm][t][f][c][k2], tf = t*128+f, k = k2*128+c
__global__ void k_wt(const float* __restrict__ convL_w, __hip_bfloat16* __restrict__ W2) {
  int i = blockIdx.x * blockDim.x + threadIdx.x;
  const int total = NBLK * 8 * 384 * 256;
  if (i >= total) return;
  int k = i & 255;
  int tf = (i >> 8) % 384;
  int wl = i / (384 * 256);
  int t = tf >> 7, f = tf & 127;
  int k2 = k >> 7, c = k & 127;
  W2[i] = __float2bfloat16(convL_w[(((size_t)(wl * 3 + t) * 128 + f) * 128 + c) * 2 + k2]);
}

__global__ void k_outsig(const float* __restrict__ signal, float* __restrict__ out) {
  int i = blockIdx.x * blockDim.x + threadIdx.x;
  if (i < NWIN) out[i] = signal[RFS + i];
}

// ---------------- per-block kernels ----------------

// CV[s][tf] = b0[tf] + prev[s]*w0[tf][0] + prev[s+1]*w0[tf][1], s in [0,1310)
__global__ void k_pre0(const float* __restrict__ prev, const float* __restrict__ w0,
                       const float* __restrict__ b0, float* __restrict__ CV) {
  int i = blockIdx.x * blockDim.x + threadIdx.x;
  if (i >= 1310 * 384) return;
  int tf = i % 384, s = i / 384;
  CV[i] = b0[tf] + prev[s] * w0[tf * 2] + prev[s + 1] * w0[tf * 2 + 1];
}

// layer 0: out[n][j][f] = act(CV[n+2j][f..] + CI(n)), 8 f per thread.
__global__ void k_layer0(const float* __restrict__ CV, const float* __restrict__ CIb,
                         __hip_bfloat16* __restrict__ out) {
  int i = blockIdx.x * blockDim.x + threadIdx.x;
  if (i >= NWIN * 256 * 16) return;
  int fg = i & 15;
  int rest = i >> 4;
  int j = rest & 255;
  int n = rest >> 8;
  int f0 = fg * 8;
  const float* cv = CV + (size_t)(n + 2 * j) * 384;
  const float* ci = CIb + (size_t)n * F;
  float4 c0a = *(const float4*)(cv + f0),       c0b = *(const float4*)(cv + f0 + 4);
  float4 c1a = *(const float4*)(cv + 128 + f0), c1b = *(const float4*)(cv + 132 + f0);
  float4 c2a = *(const float4*)(cv + 256 + f0), c2b = *(const float4*)(cv + 260 + f0);
  float4 i0a = *(const float4*)(ci + f0),       i0b = *(const float4*)(ci + f0 + 4);
  float4 i1a = *(const float4*)(ci + (size_t)NWIN * F + f0);
  float4 i1b = *(const float4*)(ci + (size_t)NWIN * F + f0 + 4);
  s16x8 res;
#pragma unroll
  for (int e = 0; e < 8; ++e) {
    float o0 = ((e < 4) ? (&c0a.x)[e] : (&c0b.x)[e - 4]) + ((e < 4) ? (&i0a.x)[e] : (&i0b.x)[e - 4]);
    float o1 = ((e < 4) ? (&c1a.x)[e] : (&c1b.x)[e - 4]) + ((e < 4) ? (&i1a.x)[e] : (&i1b.x)[e - 4]);
    float o2 = (e < 4) ? (&c2a.x)[e] : (&c2b.x)[e - 4];
    __hip_bfloat16 h = __float2bfloat16(gated_act(o0, o1, o2));
    res[e] = *(short*)&h;
  }
  *(s16x8*)(out + ((size_t)(n * 256 + j)) * F + f0) = res;
}

// Weight-stationary persistent MFMA GEMM, 512 threads = 8 waves, each wave owns
// 16 of the 128 f-cols (3 gates in regs). A tiles (BM=64) stream through
// double-buffered LDS. Epilogue stages activated bf16 in LDS, then stores
// coalesced (full 256B rows per 16-lane group).
#define BM 64
__global__ __launch_bounds__(512, 2) void k_gemm(
    const __hip_bfloat16* __restrict__ A, const __hip_bfloat16* __restrict__ W2,
    const float* __restrict__ bias, const float* __restrict__ CI0,
    const float* __restrict__ CI1, __hip_bfloat16* __restrict__ out,
    int M, int lgL) {
  __shared__ char AsB[2][BM * 512];               // 2 x 32 KB
  __shared__ char Stg[BM * 256];                  // 16 KB output staging
  const int tid = threadIdx.x;
  const int lane = tid & 63, wid = tid >> 6;
  const int ntiles = (M + BM - 1) / BM;
  const int gdx = gridDim.x;
  const int col = lane & 15, kg = lane >> 4;

  // ---- B into registers (once) ----
  const char* Wb = (const char*)W2;
  const int f = wid * 16 + col;
  s16x8 breg[3][8];
#pragma unroll
  for (int g = 0; g < 3; ++g)
#pragma unroll
    for (int ks = 0; ks < 8; ++ks)
      breg[g][ks] = *(const s16x8*)(Wb + (size_t)(g * 128 + f) * 512 + ks * 64 + kg * 16);
  const float bz0 = bias[f], bz1 = bias[128 + f], bz2 = bias[256 + f];

  const char* Ab = (const char*)A;
  const int half = lane >> 5;
  const int lin = (lane & 31) * 16;
  // ---- prologue: stage first tile into buf0 ----
#pragma unroll
  for (int it = 0; it < 4; ++it) {
    int inst = wid * 4 + it;
    int row = inst * 2 + half;
    const char* src = Ab + (size_t)blockIdx.x * (BM * 512) + row * 512 + (lin ^ ((row & 7) << 4));
    __builtin_amdgcn_global_load_lds(
        (const __attribute__((address_space(1))) unsigned int*)src,
        (__attribute__((address_space(3))) unsigned int*)(&AsB[0][0] + inst * 1024), 16, 0, 0);
  }

  int cur = 0;
  for (int t = blockIdx.x; t < ntiles; t += gdx) {
    int tn = t + gdx;
    if (tn < ntiles) {
      char* dst = &AsB[cur ^ 1][0];
#pragma unroll
      for (int it = 0; it < 4; ++it) {
        int inst = wid * 4 + it;
        int row = inst * 2 + half;
        const char* src = Ab + (size_t)tn * (BM * 512) + row * 512 + (lin ^ ((row & 7) << 4));
        __builtin_amdgcn_global_load_lds(
            (const __attribute__((address_space(1))) unsigned int*)src,
            (__attribute__((address_space(3))) unsigned int*)(dst + inst * 1024), 16, 0, 0);
      }
      VMCNT(4);            // current tile's loads done; next tile's stay in flight
    } else {
      VMCNT(0);
    }
    __builtin_amdgcn_s_barrier();
    __builtin_amdgcn_sched_barrier(0);

    f32x4 acc[4][3];
#pragma unroll
    for (int mf = 0; mf < 4; ++mf)
#pragma unroll
      for (int g = 0; g < 3; ++g) acc[mf][g] = (f32x4)(0.f);

    const char* buf = &AsB[cur][0];
    __builtin_amdgcn_s_setprio(1);
#pragma unroll
    for (int ks = 0; ks < 8; ++ks) {
      s16x8 afr[4];
#pragma unroll
      for (int mf = 0; mf < 4; ++mf) {
        int row = mf * 16 + col;
        afr[mf] = *(const s16x8*)(buf + row * 512 + ((ks * 64 + kg * 16) ^ ((row & 7) << 4)));
      }
#pragma unroll
      for (int g = 0; g < 3; ++g)
#pragma unroll
        for (int mf = 0; mf < 4; ++mf)
          acc[mf][g] = __builtin_amdgcn_mfma_f32_16x16x32_bf16(afr[mf], breg[g][ks], acc[mf][g], 0, 0, 0);
    }
    __builtin_amdgcn_s_setprio(0);

    // epilogue: act -> bf16 -> LDS staging
    int m0 = t * BM;
#pragma unroll
    for (int mf = 0; mf < 4; ++mf) {
      int mbase = mf * 16 + kg * 4;
#pragma unroll
      for (int r = 0; r < 4; ++r) {
        int mloc = mbase + r;
        int m = m0 + mloc;
        int mc = m < M ? m : M - 1;           // clamp (padding rows, not stored)
        int n = mc >> lgL;
        float o0 = acc[mf][0][r] + bz0 + CI0[n * 128 + f];
        float o1 = acc[mf][1][r] + bz1 + CI1[n * 128 + f];
        float o2 = acc[mf][2][r] + bz2;
        __hip_bfloat16 h = __float2bfloat16(gated_act(o0, o1, o2));
        *(short*)(Stg + mloc * 256 + f * 2) = *(short*)&h;
      }
    }
    __syncthreads();                          // compute+staging done (also guards restage)
    // cooperative coalesced store: 2 passes x 512 threads x 16B (full rows)
#pragma unroll
    for (int p = 0; p < 2; ++p) {
      int idx = p * 512 + tid;
      int row = idx >> 4;
      int off = (idx & 15) * 16;
      int m = m0 + row;
      if (m < M) {
        s16x8 v = *(const s16x8*)(Stg + row * 256 + off);
        *(s16x8*)((char*)out + (size_t)m * 256 + off) = v;
      }
    }
    cur ^= 1;
  }
}

// head: pre = relu(H @ pre_w^T + pre_b); mean/logvar; reparam; feedback + outputs
__global__ __launch_bounds__(256) void k_head(
    const __hip_bfloat16* __restrict__ H, const float* __restrict__ pre_w,
    const float* __restrict__ pre_b, const float* __restrict__ mean_w,
    const float* __restrict__ mean_b, const float* __restrict__ std_w,
    const float* __restrict__ std_b, const float* __restrict__ eps,
    const float* __restrict__ signal, float* __restrict__ prev_next,
    float* __restrict__ out_mean, float* __restrict__ out_logvar,
    float* __restrict__ out_tails) {
  int n = blockIdx.x;
  int tid = threadIdx.x;
  __shared__ float hv[F];
  __shared__ float red[8];
  if (tid < F) hv[tid] = __bfloat162float(H[(size_t)n * F + tid]);
  __syncthreads();
  const float* wr = pre_w + (size_t)tid * F;
  float s = pre_b[tid];
#pragma unroll
  for (int c = 0; c < F; ++c) s += hv[c] * wr[c];
  float p = fmaxf(s, 0.f);
  float m_c = p * mean_w[tid];
  float v_c = p * std_w[tid];
#pragma unroll
  for (int off = 32; off > 0; off >>= 1) {
    m_c += __shfl_down(m_c, off);
    v_c += __shfl_down(v_c, off);
  }
  int wid = tid >> 6;
  if ((tid & 63) == 0) { red[wid] = m_c; red[4 + wid] = v_c; }
  __syncthreads();
  if (tid == 0) {
    float mean = red[0] + red[1] + red[2] + red[3] + mean_b[0];
    float logv = red[4] + red[5] + red[6] + red[7] + std_b[0];
    float nx = eps[n] * expf(0.5f * logv) + mean;
    if (prev_next) prev_next[RFS + n] = nx;
    if (out_mean) { out_mean[n] = mean; out_logvar[n] = logv; }
    if (n >= NWIN - RFS) out_tails[n - (NWIN - RFS)] = nx;
  }
  if (tid == 1 && prev_next && n < RFS) prev_next[n] = signal[n];
}

// ---------------- host ----------------

extern "C" void kernel_launch(void* const* d_in, const int* in_sizes, int n_in,
                              void* d_out, int out_size, void* d_ws, size_t ws_size,
                              hipStream_t stream) {
  const float* mgc      = (const float*)d_in[0];
  const float* signal   = (const float*)d_in[1];
  const float* cond_w   = (const float*)d_in[2];
  const float* cond_b   = (const float*)d_in[3];
  const float* conv0_w  = (const float*)d_in[4];
  const float* conv0_b  = (const float*)d_in[5];
  const float* convL_w  = (const float*)d_in[6];
  const float* convL_b  = (const float*)d_in[7];
  const float* condlin_w= (const float*)d_in[8];
  const float* condlin_b= (const float*)d_in[9];
  const float* pre_w    = (const float*)d_in[10];
  const float* pre_b    = (const float*)d_in[11];
  const float* mean_w   = (const float*)d_in[12];
  const float* mean_b   = (const float*)d_in[13];
  const float* std_w    = (const float*)d_in[14];
  const float* std_b    = (const float*)d_in[15];
  const float* eps      = (const float*)d_in[16];
  float* out = (float*)d_out;

  float* wsf   = (float*)d_ws;
  float* cond  = wsf;                          // 48,000 f
  float* CI    = cond + 48000;                 // 7,372,800 f
  float* prevb = CI + 7372800;                 // 5,248 f
  float* CV    = prevb + 5248;                 // 1310*384 = 503,040 f
  float* base  = CV + 503040;
  __hip_bfloat16* W2   = (__hip_bfloat16*)base;            // 3,145,728 bf16
  __hip_bfloat16* bufA = W2 + 3145728;                     // 26,214,400 + slack
  __hip_bfloat16* bufB = bufA + 26214400 + 65536;          // 13,107,200 + slack

  k_cond<<<(NWIN * MGCS + 255) / 256, 256, 0, stream>>>(mgc, cond_w, cond_b, cond);
  k_ci<<<dim3(72, 7), 256, 0, stream>>>(cond, condlin_w, condlin_b, CI);
  k_wt<<<(NBLK * 8 * 384 * 256 + 255) / 256, 256, 0, stream>>>(convL_w, W2);
  k_outsig<<<(NWIN + 255) / 256, 256, 0, stream>>>(signal, out);

  for (int blk = 0; blk < NBLK; ++blk) {
    const float* prev = (blk == 0) ? signal : (prevb + (size_t)(blk - 1) * 1312);
    const float* CIb = CI + (size_t)(blk * NLAY) * 2 * NWIN * F;
    k_pre0<<<(1310 * 384 + 255) / 256, 256, 0, stream>>>(
        prev, conv0_w + (size_t)blk * 3 * F * 2, conv0_b + (size_t)blk * 3 * F, CV);
    k_layer0<<<(NWIN * 256 * 16 + 255) / 256, 256, 0, stream>>>(CV, CIb, bufA);

    __hip_bfloat16* cur = bufA;
    __hip_bfloat16* nxt = bufB;
    for (int l = 1; l < NLAY; ++l) {
      int Lout = 256 >> l;
      int M = NWIN * Lout;
      const float* ci0 = CI + ((size_t)((blk * NLAY + l) * 2 + 0)) * NWIN * F;
      const float* ci1 = CI + ((size_t)((blk * NLAY + l) * 2 + 1)) * NWIN * F;
      const __hip_bfloat16* wt = W2 + (size_t)(blk * 8 + (l - 1)) * 384 * 256;
      const float* bs = convL_b + (size_t)((blk * 8 + (l - 1)) * 3) * F;
      int ntiles = (M + BM - 1) / BM;
      int gx = ntiles < 512 ? ntiles : 512;
      k_gemm<<<dim3(gx), 512, 0, stream>>>(cur, wt, bs, ci0, ci1, nxt, M, 8 - l);
      __hip_bfloat16* tmp = cur; cur = nxt; nxt = tmp;
    }
    k_head<<<NWIN, 256, 0, stream>>>(
        cur, pre_w + (size_t)blk * 256 * F, pre_b + (size_t)blk * 256,
        mean_w + (size_t)blk * 256, mean_b + blk,
        std_w + (size_t)blk * 256, std_b + blk,
        eps + (size_t)blk * NWIN, signal,
        (blk < 3) ? (prevb + (size_t)blk * 1312) : nullptr,
        (blk == 3) ? (out + 800) : nullptr,
        (blk == 3) ? (out + 1600) : nullptr,
        out + 2400 + (size_t)blk * 512);
  }
}